// Round 2
// baseline (1482.929 us; speedup 1.0000x reference)
//
#include <hip/hip_runtime.h>

#define NN   512
#define NN2  (512 * 512)
#define BB   64
#define TILE 64
#define HROW 10
#define RROW (TILE + 2 * HROW)   // 84 rows in region
#define HCOL 12                  // 12 so region cols stay float4-aligned vs global
#define RCOL (TILE + 2 * HCOL)   // 88 cols in region
#define VC   (RCOL / 4)          // 22 float4 groups per row
#define UNITS (RROW * VC)        // 1848
#define KMAX  ((UNITS + 255) / 256)  // 8
#define ITERS 10

__device__ __forceinline__ float sigf(float x) {
    return 1.0f / (1.0f + __expf(-x));
}

// mask with cheap early-out; beyond the cutoffs mask < ~2e-12.
__device__ __forceinline__ float maskf(float s, float t, float L) {
    if (fabsf(t) > 30.f || s < -30.f || s > L + 30.f) return 0.f;
    return sigf(3.f - fabsf(t)) * sigf(s) * sigf(L - s);
}

// Pass 1: splat moved mass into zeroed ws. Only band cells do atomics.
__global__ void __launch_bounds__(256) splat_kernel(
        const float* __restrict__ occ,
        const float* __restrict__ as_,
        const float* __restrict__ ae_,
        float* __restrict__ ws) {
    int gid = blockIdx.x * 256 + threadIdx.x;   // float4-group id
    int b   = gid >> 16;                        // 65536 groups per batch
    int rem = gid & 65535;
    int i   = rem >> 7;                         // row
    int j0  = (rem & 127) << 2;                 // col base (aligned)

    float p0x = as_[2 * b], p0y = as_[2 * b + 1];
    float p1x = ae_[2 * b], p1y = ae_[2 * b + 1];
    float dx = p1x - p0x, dy = p1y - p0y;
    float L  = sqrtf(dx * dx + dy * dy + 1e-12f);
    float u0 = dx / L, u1 = dy / L;

    const float* ob = occ + ((size_t)b << 18);
    float*       wb = ws  + ((size_t)b << 18);
    float4 rv = *reinterpret_cast<const float4*>(ob + i * NN + j0);
    float rx = (float)i - p0x;

    #pragma unroll
    for (int k = 0; k < 4; ++k) {
        float rho = ((const float*)&rv)[k];
        float jy  = (float)(j0 + k);
        float ry  = jy - p0y;
        float s   = rx * u0 + ry * u1;
        float t   = -rx * u1 + ry * u0;
        if (fabsf(t) > 30.f || s < -30.f || s > L + 30.f) continue;
        float mask  = sigf(3.f - fabsf(t)) * sigf(s) * sigf(L - s);
        float moved = rho * mask;
        if (moved <= 1e-10f) continue;
        float disp = fmaxf(L - s, 0.f);
        float xf = (float)i + disp * u0;
        float yf = jy + disp * u1;
        float x0 = floorf(xf), y0 = floorf(yf);
        float fx = xf - x0,    fy = yf - y0;
        int xi = (int)x0, yi = (int)y0;
        #pragma unroll
        for (int dxc = 0; dxc < 2; ++dxc) {
            #pragma unroll
            for (int dyc = 0; dyc < 2; ++dyc) {
                int ti = xi + dxc, tj = yi + dyc;
                float w = (dxc ? fx : 1.f - fx) * (dyc ? fy : 1.f - fy);
                if (ti >= 0 && ti < NN && tj >= 0 && tj < NN)
                    atomicAdd(wb + ti * NN + tj, w * moved);
            }
        }
    }
}

// Pass 2: per 64x64 output tile, build r0 = occ*(1-mask) + ws in a haloed
// LDS region and run all 10 redistribution iterations on-chip.
__global__ void __launch_bounds__(256, 4) tile_kernel(
        const float* __restrict__ occ,
        const float* __restrict__ ws,
        const float* __restrict__ as_,
        const float* __restrict__ ae_,
        float* __restrict__ out) {
    __shared__ float exc[RROW * RCOL];

    int bid  = blockIdx.x;
    int b    = bid >> 6;
    int tile = bid & 63;
    int gi0  = (tile >> 3) * TILE - HROW;
    int gj0  = (tile & 7)  * TILE - HCOL;

    float p0x = as_[2 * b], p0y = as_[2 * b + 1];
    float p1x = ae_[2 * b], p1y = ae_[2 * b + 1];
    float dx = p1x - p0x, dy = p1y - p0y;
    float L  = sqrtf(dx * dx + dy * dy + 1e-12f);
    float pu0 = dx / L, pu1 = dy / L;          // push direction
    float dn  = sqrtf(dx * dx + dy * dy);
    bool active = dn > 1e-6f;
    float rdn = fmaxf(dn, 1e-6f);
    float ru0 = dx / rdn, ru1 = dy / rdn;      // redist direction
    float s0f = floorf(ru0), s1f = floorf(ru1);
    float f0 = ru0 - s0f, f1 = ru1 - s1f;
    int oi = -(int)s0f;                        // in {0,1}
    int oj = -(int)s1f;
    float wA0 = 1.f - f0, wB0 = f0;
    float wA1 = 1.f - f1, wB1 = f1;

    const float* ob  = occ + ((size_t)b << 18);
    const float* wb  = ws  + ((size_t)b << 18);
    float*      outb = out + ((size_t)b << 18);

    int li_[KMAX], lj_[KMAX];
    #pragma unroll
    for (int k = 0; k < KMAX; ++k) {
        int u = threadIdx.x + k * 256;
        li_[k] = u / VC;
        lj_[k] = (u % VC) * 4;
    }

    float4 r[KMAX];
    // ---- load region: r0 = occ*(1-mask) + ws ----
    #pragma unroll
    for (int k = 0; k < KMAX; ++k) {
        int u = threadIdx.x + k * 256;
        float4 v = make_float4(0.f, 0.f, 0.f, 0.f);
        if (u < UNITS) {
            int li = li_[k], lj = lj_[k];
            int gi = gi0 + li, gj = gj0 + lj;
            if (gi >= 0 && gi < NN) {
                float rx = (float)gi - p0x;
                if (gj >= 0 && gj + 3 < NN) {
                    float4 o4 = *reinterpret_cast<const float4*>(ob + gi * NN + gj);
                    float4 w4 = *reinterpret_cast<const float4*>(wb + gi * NN + gj);
                    float* op = (float*)&o4;
                    float* wp = (float*)&w4;
                    float* vp = (float*)&v;
                    #pragma unroll
                    for (int e = 0; e < 4; ++e) {
                        float ry = (float)(gj + e) - p0y;
                        float s  = rx * pu0 + ry * pu1;
                        float t  = -rx * pu1 + ry * pu0;
                        vp[e] = op[e] * (1.f - maskf(s, t, L)) + wp[e];
                    }
                } else {
                    float* vp = (float*)&v;
                    #pragma unroll
                    for (int e = 0; e < 4; ++e) {
                        int gje = gj + e;
                        if (gje >= 0 && gje < NN) {
                            float rho = ob[gi * NN + gje];
                            float wsv = wb[gi * NN + gje];
                            float ry = (float)gje - p0y;
                            float s  = rx * pu0 + ry * pu1;
                            float t  = -rx * pu1 + ry * pu0;
                            vp[e] = rho * (1.f - maskf(s, t, L)) + wsv;
                        }
                    }
                }
            }
        }
        r[k] = v;
    }

    // ---- 10 on-chip iterations ----
    if (active) {
        for (int it = 0; it < ITERS; ++it) {
            #pragma unroll
            for (int k = 0; k < KMAX; ++k) {
                int u = threadIdx.x + k * 256;
                if (u < UNITS) {
                    int li = li_[k], lj = lj_[k];
                    int gi = gi0 + li, gj = gj0 + lj;
                    bool rowok = (gi >= 0 && gi < NN);
                    float4 rv = r[k];
                    float4 e;
                    e.x = (rowok && (unsigned)(gj + 0) < NN) ? fmaxf(rv.x - 1.f, 0.f) : 0.f;
                    e.y = (rowok && (unsigned)(gj + 1) < NN) ? fmaxf(rv.y - 1.f, 0.f) : 0.f;
                    e.z = (rowok && (unsigned)(gj + 2) < NN) ? fmaxf(rv.z - 1.f, 0.f) : 0.f;
                    e.w = (rowok && (unsigned)(gj + 3) < NN) ? fmaxf(rv.w - 1.f, 0.f) : 0.f;
                    *reinterpret_cast<float4*>(&exc[li * RCOL + lj]) = e;
                }
            }
            __syncthreads();
            #pragma unroll
            for (int k = 0; k < KMAX; ++k) {
                int u = threadIdx.x + k * 256;
                if (u < UNITS) {
                    int li = li_[k], lj = lj_[k];
                    int rA = li + oi;       // weight wA0
                    int rB = rA - 1;        // weight wB0
                    rA = min(max(rA, 0), RROW - 1);
                    rB = min(max(rB, 0), RROW - 1);
                    int c0 = lj + oj - 1;
                    float eA[5], eB[5];
                    #pragma unroll
                    for (int m = 0; m < 5; ++m) {
                        int c = min(max(c0 + m, 0), RCOL - 1);
                        eA[m] = exc[rA * RCOL + c];
                        eB[m] = exc[rB * RCOL + c];
                    }
                    float4 rv = r[k];
                    float* rp = (float*)&rv;
                    #pragma unroll
                    for (int q = 0; q < 4; ++q) {
                        float rowA = wA1 * eA[q + 1] + wB1 * eA[q];
                        float rowB = wA1 * eB[q + 1] + wB1 * eB[q];
                        float accv = wA0 * rowA + wB0 * rowB;
                        rp[q] = rp[q] - fmaxf(rp[q] - 1.f, 0.f) + accv;
                    }
                    r[k] = rv;
                }
            }
            __syncthreads();
        }
    }

    // ---- write 64x64 interior ----
    #pragma unroll
    for (int k = 0; k < KMAX; ++k) {
        int u = threadIdx.x + k * 256;
        if (u < UNITS) {
            int li = li_[k], lj = lj_[k];
            if (li >= HROW && li < HROW + TILE && lj >= HCOL && lj < HCOL + TILE) {
                int gi = gi0 + li, gj = gj0 + lj;
                *reinterpret_cast<float4*>(outb + gi * NN + gj) = r[k];
            }
        }
    }
}

extern "C" void kernel_launch(void* const* d_in, const int* in_sizes, int n_in,
                              void* d_out, int out_size, void* d_ws, size_t ws_size,
                              hipStream_t stream) {
    const float* occ = (const float*)d_in[0];
    const float* as_ = (const float*)d_in[1];
    const float* ae_ = (const float*)d_in[2];
    float* out = (float*)d_out;
    float* ws  = (float*)d_ws;

    const size_t total_bytes = (size_t)BB * NN2 * sizeof(float);
    hipMemsetAsync(ws, 0, total_bytes, stream);

    const int splat_blocks = (BB * NN2 / 4) / 256;   // 16384
    splat_kernel<<<splat_blocks, 256, 0, stream>>>(occ, as_, ae_, ws);

    const int tile_blocks = BB * (NN / TILE) * (NN / TILE);  // 4096
    tile_kernel<<<tile_blocks, 256, 0, stream>>>(occ, ws, as_, ae_, out);
}

// Round 3
// 550.256 us; speedup vs baseline: 2.6950x; 2.6950x over previous
//
#include <hip/hip_runtime.h>

#define NN   512
#define NN2  (NN * NN)
#define BB   64
#define TILE 64
#define HROW 10
#define HCOL 12
#define RROW (TILE + 2 * HROW)     // 84 region rows
#define LCOL (TILE + 2 * HCOL)     // 88 logical region cols
#define LROW 89                    // physical LDS row stride in words (ODD -> bank spread)
#define UNITS (RROW * (LCOL / 4))  // 1848 float4-units
#define ITERS 10
#define TPB  512

__device__ __forceinline__ float sigf(float x) { return 1.0f / (1.0f + __expf(-x)); }

__device__ __forceinline__ float maskf(float s, float t, float L) {
    if (fabsf(t) > 30.f || s < -30.f || s > L + 30.f) return 0.f;
    return sigf(3.f - fabsf(t)) * sigf(s) * sigf(L - s);
}

// ---------------- Pass 1: splat moved mass into zeroed ws ----------------
__global__ void __launch_bounds__(256) splat_kernel(
        const float* __restrict__ occ,
        const float* __restrict__ as_,
        const float* __restrict__ ae_,
        float* __restrict__ ws) {
    int gid = blockIdx.x * 256 + threadIdx.x;   // float4-group id
    int b   = gid >> 16;
    int rem = gid & 65535;
    int i   = rem >> 7;
    int j0  = (rem & 127) << 2;

    float p0x = as_[2 * b], p0y = as_[2 * b + 1];
    float p1x = ae_[2 * b], p1y = ae_[2 * b + 1];
    float dx = p1x - p0x, dy = p1y - p0y;
    float L  = sqrtf(dx * dx + dy * dy + 1e-12f);
    float u0 = dx / L, u1 = dy / L;

    float rx = (float)i - p0x;
    float ry0 = (float)j0 - p0y;
    float s0 = rx * u0 + ry0 * u1;
    float t0 = -rx * u1 + ry0 * u0;
    float s3 = s0 + 3.f * u1;
    float t3 = t0 + 3.f * u0;
    // whole-group band rejection BEFORE touching occ (s,t linear in j)
    if (fminf(t0, t3) > 30.f || fmaxf(t0, t3) < -30.f) return;
    if (fminf(s0, s3) > L + 30.f || fmaxf(s0, s3) < -30.f) return;

    const float* ob = occ + ((size_t)b << 18);
    float*       wp = ws  + ((size_t)b << 18);
    float4 rv = *reinterpret_cast<const float4*>(ob + i * NN + j0);

    #pragma unroll
    for (int k = 0; k < 4; ++k) {
        float rho = (k == 0) ? rv.x : (k == 1) ? rv.y : (k == 2) ? rv.z : rv.w;
        float jy  = (float)(j0 + k);
        float ry  = jy - p0y;
        float s   = rx * u0 + ry * u1;
        float t   = -rx * u1 + ry * u0;
        if (fabsf(t) > 30.f || s < -30.f || s > L + 30.f) continue;
        float mask  = sigf(3.f - fabsf(t)) * sigf(s) * sigf(L - s);
        float moved = rho * mask;
        if (moved <= 1e-10f) continue;
        float disp = fmaxf(L - s, 0.f);
        float xf = (float)i + disp * u0;
        float yf = jy + disp * u1;
        float x0 = floorf(xf), y0 = floorf(yf);
        float fx = xf - x0,    fy = yf - y0;
        int xi = (int)x0, yi = (int)y0;
        #pragma unroll
        for (int dxc = 0; dxc < 2; ++dxc) {
            #pragma unroll
            for (int dyc = 0; dyc < 2; ++dyc) {
                int ti = xi + dxc, tj = yi + dyc;
                float w = (dxc ? fx : 1.f - fx) * (dyc ? fy : 1.f - fy);
                if (ti >= 0 && ti < NN && tj >= 0 && tj < NN)
                    atomicAdd(wp + ti * NN + tj, w * moved);
            }
        }
    }
}

// ---------------- Pass 2: fused base + 10 redistribution iterations ----------------
// Macro-expanded 4 unit-instances per thread: guaranteed-static register residency.

#define UNIT_INIT(K, UEXPR)                                                          \
    const int u##K  = (UEXPR);                                                       \
    const int li##K = u##K / 22;                                                     \
    const int lj##K = (u##K - li##K * 22) * 4;                                       \
    float4 r##K, vm##K;                                                              \
    {                                                                                \
        int gi = gi0 + li##K, gj = gj0 + lj##K;                                      \
        bool rok = (gi >= 0) && (gi < NN);                                           \
        vm##K.x = (rok && (unsigned)(gj + 0) < NN) ? 1.f : 0.f;                      \
        vm##K.y = (rok && (unsigned)(gj + 1) < NN) ? 1.f : 0.f;                      \
        vm##K.z = (rok && (unsigned)(gj + 2) < NN) ? 1.f : 0.f;                      \
        vm##K.w = (rok && (unsigned)(gj + 3) < NN) ? 1.f : 0.f;                      \
        float4 v = make_float4(0.f, 0.f, 0.f, 0.f);                                  \
        if (rok) {                                                                   \
            float rxq = (float)gi - p0x;                                             \
            const float* orow = ob + gi * NN;                                        \
            const float* wrow = wq + gi * NN;                                        \
            if (gj >= 0 && gj + 3 < NN) {                                            \
                float4 o4 = *reinterpret_cast<const float4*>(orow + gj);             \
                float4 w4 = *reinterpret_cast<const float4*>(wrow + gj);             \
                float ry;                                                            \
                ry = (float)(gj + 0) - p0y;                                          \
                v.x = o4.x * (1.f - maskf(rxq*pu0 + ry*pu1, -rxq*pu1 + ry*pu0, L)) + w4.x; \
                ry = (float)(gj + 1) - p0y;                                          \
                v.y = o4.y * (1.f - maskf(rxq*pu0 + ry*pu1, -rxq*pu1 + ry*pu0, L)) + w4.y; \
                ry = (float)(gj + 2) - p0y;                                          \
                v.z = o4.z * (1.f - maskf(rxq*pu0 + ry*pu1, -rxq*pu1 + ry*pu0, L)) + w4.z; \
                ry = (float)(gj + 3) - p0y;                                          \
                v.w = o4.w * (1.f - maskf(rxq*pu0 + ry*pu1, -rxq*pu1 + ry*pu0, L)) + w4.w; \
            } else {                                                                 \
                float ry;                                                            \
                if (vm##K.x > 0.f) { ry = (float)(gj+0) - p0y;                       \
                    v.x = orow[gj+0] * (1.f - maskf(rxq*pu0 + ry*pu1, -rxq*pu1 + ry*pu0, L)) + wrow[gj+0]; } \
                if (vm##K.y > 0.f) { ry = (float)(gj+1) - p0y;                       \
                    v.y = orow[gj+1] * (1.f - maskf(rxq*pu0 + ry*pu1, -rxq*pu1 + ry*pu0, L)) + wrow[gj+1]; } \
                if (vm##K.z > 0.f) { ry = (float)(gj+2) - p0y;                       \
                    v.z = orow[gj+2] * (1.f - maskf(rxq*pu0 + ry*pu1, -rxq*pu1 + ry*pu0, L)) + wrow[gj+2]; } \
                if (vm##K.w > 0.f) { ry = (float)(gj+3) - p0y;                       \
                    v.w = orow[gj+3] * (1.f - maskf(rxq*pu0 + ry*pu1, -rxq*pu1 + ry*pu0, L)) + wrow[gj+3]; } \
            }                                                                        \
        }                                                                            \
        r##K = v;                                                                    \
    }                                                                                \
    const int rA##K = min(max(li##K + oi, 0), RROW - 1);                             \
    const int dB##K = (min(max(li##K + oi - 1, 0), RROW - 1) - rA##K) * LROW;        \
    const int wa##K = li##K * LROW + lj##K;                                          \
    const int aA0##K = rA##K * LROW + max(lj##K + oj - 1, 0);                        \
    const int aA1##K = rA##K * LROW + (lj##K + oj + 0);                              \
    const int aA2##K = rA##K * LROW + (lj##K + oj + 1);                              \
    const int aA3##K = rA##K * LROW + (lj##K + oj + 2);                              \
    const int aA4##K = rA##K * LROW + min(lj##K + oj + 3, LCOL - 1);

#define UNIT_STORE(K)                                                                \
    smem[wa##K + 0] = fmaxf(r##K.x - 1.f, 0.f);                                      \
    smem[wa##K + 1] = fmaxf(r##K.y - 1.f, 0.f);                                      \
    smem[wa##K + 2] = fmaxf(r##K.z - 1.f, 0.f);                                      \
    smem[wa##K + 3] = fmaxf(r##K.w - 1.f, 0.f);

#define UNIT_GATHER(K) {                                                             \
    float eA0 = smem[aA0##K], eA1 = smem[aA1##K], eA2 = smem[aA2##K];                \
    float eA3 = smem[aA3##K], eA4 = smem[aA4##K];                                    \
    float eB0 = smem[aA0##K + dB##K], eB1 = smem[aA1##K + dB##K];                    \
    float eB2 = smem[aA2##K + dB##K], eB3 = smem[aA3##K + dB##K];                    \
    float eB4 = smem[aA4##K + dB##K];                                                \
    float g;                                                                         \
    g = wA0 * (wA1 * eA1 + wB1 * eA0) + wB0 * (wA1 * eB1 + wB1 * eB0);               \
    r##K.x = (fminf(r##K.x, 1.f) + g) * vm##K.x;                                     \
    g = wA0 * (wA1 * eA2 + wB1 * eA1) + wB0 * (wA1 * eB2 + wB1 * eB1);               \
    r##K.y = (fminf(r##K.y, 1.f) + g) * vm##K.y;                                     \
    g = wA0 * (wA1 * eA3 + wB1 * eA2) + wB0 * (wA1 * eB3 + wB1 * eB2);               \
    r##K.z = (fminf(r##K.z, 1.f) + g) * vm##K.z;                                     \
    g = wA0 * (wA1 * eA4 + wB1 * eA3) + wB0 * (wA1 * eB4 + wB1 * eB3);               \
    r##K.w = (fminf(r##K.w, 1.f) + g) * vm##K.w; }

#define UNIT_WRITE(K)                                                                \
    if (li##K >= HROW && li##K < HROW + TILE && lj##K >= HCOL && lj##K < HCOL + TILE) { \
        *reinterpret_cast<float4*>(outb + (gi0 + li##K) * NN + (gj0 + lj##K)) = r##K; }

__global__ void __launch_bounds__(TPB, 4) tile_kernel(
        const float* __restrict__ occ,
        const float* __restrict__ ws,
        const float* __restrict__ as_,
        const float* __restrict__ ae_,
        float* __restrict__ out) {
    __shared__ float smem[RROW * LROW];

    const int bid  = blockIdx.x;
    const int b    = bid >> 6;
    const int tile = bid & 63;
    const int gi0  = (tile >> 3) * TILE - HROW;
    const int gj0  = (tile & 7)  * TILE - HCOL;

    const float p0x = as_[2 * b], p0y = as_[2 * b + 1];
    const float p1x = ae_[2 * b], p1y = ae_[2 * b + 1];
    const float dx = p1x - p0x, dy = p1y - p0y;
    const float L  = sqrtf(dx * dx + dy * dy + 1e-12f);
    const float pu0 = dx / L, pu1 = dy / L;
    const float dn  = sqrtf(dx * dx + dy * dy);
    const bool active = dn > 1e-6f;
    const float rdn = fmaxf(dn, 1e-6f);
    const float ru0 = dx / rdn, ru1 = dy / rdn;
    const float s0f = floorf(ru0), s1f = floorf(ru1);
    const float f0 = ru0 - s0f, f1 = ru1 - s1f;
    const int oi = -(int)s0f;
    const int oj = -(int)s1f;
    const float wA0 = 1.f - f0, wB0 = f0;
    const float wA1 = 1.f - f1, wB1 = f1;

    const float* ob   = occ + ((size_t)b << 18);
    const float* wq   = ws  + ((size_t)b << 18);
    float*       outb = out + ((size_t)b << 18);

    const int tid = threadIdx.x;
    UNIT_INIT(0, tid)
    UNIT_INIT(1, tid + TPB)
    UNIT_INIT(2, tid + 2 * TPB)
    UNIT_INIT(3, min(tid + 3 * TPB, UNITS - 1))

    if (active) {
        for (int it = 0; it < ITERS; ++it) {
            UNIT_STORE(0) UNIT_STORE(1) UNIT_STORE(2) UNIT_STORE(3)
            __syncthreads();
            UNIT_GATHER(0) UNIT_GATHER(1) UNIT_GATHER(2) UNIT_GATHER(3)
            __syncthreads();
        }
    }

    UNIT_WRITE(0)
    UNIT_WRITE(1)
    UNIT_WRITE(2)
    UNIT_WRITE(3)
}

extern "C" void kernel_launch(void* const* d_in, const int* in_sizes, int n_in,
                              void* d_out, int out_size, void* d_ws, size_t ws_size,
                              hipStream_t stream) {
    const float* occ = (const float*)d_in[0];
    const float* as_ = (const float*)d_in[1];
    const float* ae_ = (const float*)d_in[2];
    float* out = (float*)d_out;
    float* ws  = (float*)d_ws;

    const size_t total_bytes = (size_t)BB * NN2 * sizeof(float);
    hipMemsetAsync(ws, 0, total_bytes, stream);

    const int splat_blocks = (BB * NN2 / 4) / 256;   // 16384
    splat_kernel<<<splat_blocks, 256, 0, stream>>>(occ, as_, ae_, ws);

    const int tile_blocks = BB * (NN / TILE) * (NN / TILE);  // 4096
    tile_kernel<<<tile_blocks, TPB, 0, stream>>>(occ, ws, as_, ae_, out);
}

// Round 4
// 238.923 us; speedup vs baseline: 6.2067x; 2.3031x over previous
//
#include <hip/hip_runtime.h>

#define NN   512
#define NN2  (NN * NN)
#define BB   64
#define TILE 64
#define HROW 10
#define HCOL 12
#define RROW (TILE + 2 * HROW)     // 84 region rows
#define LCOL (TILE + 2 * HCOL)     // 88 logical region cols
#define LROW 89                    // LDS row stride (ODD -> bank spread)
#define UNITS (RROW * (LCOL / 4))  // 1848
#define ITERS 10
#define TPB  512
#define WM   68                    // landing-window dim & stride
#define WWIN (WM * WM)             // 4624 floats
#define EXP  16                    // iteration-skip safety margin

__device__ __forceinline__ float sigf(float x) { return 1.0f / (1.0f + __expf(-x)); }

__device__ __forceinline__ float maskf(float s, float t, float L) {
    if (fabsf(t) > 30.f || s < -30.f || s > L + 30.f) return 0.f;
    return sigf(3.f - fabsf(t)) * sigf(s) * sigf(L - s);
}

// r0 = pushed density at (gi,gj): base + landing-window mass. s>=L (or degenerate
// direction) => cell splats exactly onto itself with weight 1 => net rho.
__device__ __forceinline__ float r0_elem(float o, int gi, int gj,
        float p0x, float p0y, float pu0, float pu1, float L,
        bool degen, int wx0, int wy0, const float* __restrict__ wsb) {
    float rx = (float)gi - p0x, ry = (float)gj - p0y;
    float s = rx * pu0 + ry * pu1;
    float t = -rx * pu1 + ry * pu0;
    float m = maskf(s, t, L);
    float v = (degen || s >= L) ? o : o * (1.f - m);
    int cx = gi - wx0, cy = gj - wy0;
    if ((unsigned)cx < (unsigned)WM && (unsigned)cy < (unsigned)WM)
        v += wsb[cx * WM + cy];
    return v;
}

// ---------------- Pass 1: one block per batch, LDS landing window ----------------
__global__ void __launch_bounds__(1024) splat_kernel(
        const float* __restrict__ occ,
        const float* __restrict__ as_,
        const float* __restrict__ ae_,
        float* __restrict__ ws) {
    __shared__ float win[WWIN];
    const int b   = blockIdx.x;
    const int tid = threadIdx.x;

    const float p0x = as_[2 * b], p0y = as_[2 * b + 1];
    const float p1x = ae_[2 * b], p1y = ae_[2 * b + 1];
    const float dx = p1x - p0x, dy = p1y - p0y;
    const float L  = sqrtf(dx * dx + dy * dy + 1e-12f);
    const float u0 = dx / L, u1 = dy / L;
    const float au0 = fabsf(u0), au1 = fabsf(u1);
    const int wx0 = (int)floorf(p1x - 32.f * au1);
    const int wy0 = (int)floorf(p1y - 32.f * au0);
    const bool degen = (dx == 0.f && dy == 0.f);

    for (int k = tid; k < WWIN; k += 1024) win[k] = 0.f;
    __syncthreads();

    if (!degen) {
        const float* ob = occ + ((size_t)b << 18);
        // lane-fast axis = the one where t changes fastest -> no same-address runs
        const bool sw = au1 > au0;

        for (int g = tid; g < 65536; g += 1024) {
            int a  = g >> 7;            // slow coord
            int c0 = (g & 127) << 2;    // fast coord base (4 cells)
            float i0f, j0f, di_, dj_;
            if (!sw) { i0f = (float)a;  j0f = (float)c0; di_ = 0.f; dj_ = 3.f; }
            else     { i0f = (float)c0; j0f = (float)a;  di_ = 3.f; dj_ = 0.f; }
            float rx0 = i0f - p0x, ry0 = j0f - p0y;
            float s00 = rx0 * u0 + ry0 * u1;
            float t00 = -rx0 * u1 + ry0 * u0;
            float s11 = s00 + di_ * u0 + dj_ * u1;
            float t11 = t00 - di_ * u1 + dj_ * u0;
            if (fminf(t00, t11) > 30.f || fmaxf(t00, t11) < -30.f) continue;
            if (fminf(s00, s11) > L + 30.f || fmaxf(s00, s11) < -30.f) continue;

            float4 rv;
            if (!sw) {
                rv = *reinterpret_cast<const float4*>(ob + a * NN + c0);
            } else {
                rv.x = ob[(c0 + 0) * NN + a];
                rv.y = ob[(c0 + 1) * NN + a];
                rv.z = ob[(c0 + 2) * NN + a];
                rv.w = ob[(c0 + 3) * NN + a];
            }
            #pragma unroll
            for (int k = 0; k < 4; ++k) {
                float rho = (k == 0) ? rv.x : (k == 1) ? rv.y : (k == 2) ? rv.z : rv.w;
                float fk = (float)k;
                float s = s00 + (sw ? fk * u0 : fk * u1);
                float t = t00 + (sw ? -fk * u1 : fk * u0);
                if (fabsf(t) > 30.f || s < -30.f || s >= L) continue;  // s>=L: self-splat
                float mask  = sigf(3.f - fabsf(t)) * sigf(s) * sigf(L - s);
                float moved = rho * mask;
                if (moved <= 1e-10f) continue;
                // landing depends only on t: p1 + t*n
                float xf = p1x - t * u1;
                float yf = p1y + t * u0;
                float x0 = floorf(xf), y0 = floorf(yf);
                float fx = xf - x0, fy = yf - y0;
                int base = ((int)x0 - wx0) * WM + ((int)y0 - wy0);
                atomicAdd(&win[base],          (1.f - fx) * (1.f - fy) * moved);
                atomicAdd(&win[base + 1],      (1.f - fx) * fy * moved);
                atomicAdd(&win[base + WM],     fx * (1.f - fy) * moved);
                atomicAdd(&win[base + WM + 1], fx * fy * moved);
            }
        }
    }
    __syncthreads();
    float* wsb = ws + (size_t)b * WWIN;
    for (int k = tid; k < WWIN; k += 1024) wsb[k] = win[k];
}

// ---------------- Pass 2: fused base + window + 10 iterations ----------------
#define UNIT_INIT(K, UEXPR)                                                          \
    const int u##K  = (UEXPR);                                                       \
    const int li##K = u##K / 22;                                                     \
    const int lj##K = (u##K - li##K * 22) * 4;                                       \
    float4 r##K, vm##K;                                                              \
    {                                                                                \
        int gi = gi0 + li##K, gj = gj0 + lj##K;                                      \
        bool rok = (gi >= 0) && (gi < NN);                                           \
        vm##K.x = (rok && (unsigned)(gj + 0) < NN) ? 1.f : 0.f;                      \
        vm##K.y = (rok && (unsigned)(gj + 1) < NN) ? 1.f : 0.f;                      \
        vm##K.z = (rok && (unsigned)(gj + 2) < NN) ? 1.f : 0.f;                      \
        vm##K.w = (rok && (unsigned)(gj + 3) < NN) ? 1.f : 0.f;                      \
        float4 v = make_float4(0.f, 0.f, 0.f, 0.f);                                  \
        if (rok) {                                                                   \
            const float* orow = ob + gi * NN;                                        \
            if (gj >= 0 && gj <= NN - 4) {                                           \
                float4 o4 = *reinterpret_cast<const float4*>(orow + gj);             \
                v.x = r0_elem(o4.x, gi, gj + 0, p0x, p0y, pu0, pu1, L, degen, wx0, wy0, wsb); \
                v.y = r0_elem(o4.y, gi, gj + 1, p0x, p0y, pu0, pu1, L, degen, wx0, wy0, wsb); \
                v.z = r0_elem(o4.z, gi, gj + 2, p0x, p0y, pu0, pu1, L, degen, wx0, wy0, wsb); \
                v.w = r0_elem(o4.w, gi, gj + 3, p0x, p0y, pu0, pu1, L, degen, wx0, wy0, wsb); \
            } else {                                                                 \
                if (vm##K.x > 0.f) v.x = r0_elem(orow[gj + 0], gi, gj + 0, p0x, p0y, pu0, pu1, L, degen, wx0, wy0, wsb); \
                if (vm##K.y > 0.f) v.y = r0_elem(orow[gj + 1], gi, gj + 1, p0x, p0y, pu0, pu1, L, degen, wx0, wy0, wsb); \
                if (vm##K.z > 0.f) v.z = r0_elem(orow[gj + 2], gi, gj + 2, p0x, p0y, pu0, pu1, L, degen, wx0, wy0, wsb); \
                if (vm##K.w > 0.f) v.w = r0_elem(orow[gj + 3], gi, gj + 3, p0x, p0y, pu0, pu1, L, degen, wx0, wy0, wsb); \
            }                                                                        \
        }                                                                            \
        r##K = v;                                                                    \
    }                                                                                \
    const int rA##K = min(max(li##K + oi, 0), RROW - 1);                             \
    const int dB##K = (min(max(li##K + oi - 1, 0), RROW - 1) - rA##K) * LROW;        \
    const int wa##K = li##K * LROW + lj##K;                                          \
    const int aA0##K = rA##K * LROW + max(lj##K + oj - 1, 0);                        \
    const int aA1##K = rA##K * LROW + (lj##K + oj + 0);                              \
    const int aA2##K = rA##K * LROW + (lj##K + oj + 1);                              \
    const int aA3##K = rA##K * LROW + (lj##K + oj + 2);                              \
    const int aA4##K = rA##K * LROW + min(lj##K + oj + 3, LCOL - 1);

#define UNIT_STORE(K)                                                                \
    smem[wa##K + 0] = fmaxf(r##K.x - 1.f, 0.f);                                      \
    smem[wa##K + 1] = fmaxf(r##K.y - 1.f, 0.f);                                      \
    smem[wa##K + 2] = fmaxf(r##K.z - 1.f, 0.f);                                      \
    smem[wa##K + 3] = fmaxf(r##K.w - 1.f, 0.f);

#define UNIT_GATHER(K) {                                                             \
    float eA0 = smem[aA0##K], eA1 = smem[aA1##K], eA2 = smem[aA2##K];                \
    float eA3 = smem[aA3##K], eA4 = smem[aA4##K];                                    \
    float eB0 = smem[aA0##K + dB##K], eB1 = smem[aA1##K + dB##K];                    \
    float eB2 = smem[aA2##K + dB##K], eB3 = smem[aA3##K + dB##K];                    \
    float eB4 = smem[aA4##K + dB##K];                                                \
    float g;                                                                         \
    g = wA0 * (wA1 * eA1 + wB1 * eA0) + wB0 * (wA1 * eB1 + wB1 * eB0);               \
    r##K.x = (fminf(r##K.x, 1.f) + g) * vm##K.x;                                     \
    g = wA0 * (wA1 * eA2 + wB1 * eA1) + wB0 * (wA1 * eB2 + wB1 * eB1);               \
    r##K.y = (fminf(r##K.y, 1.f) + g) * vm##K.y;                                     \
    g = wA0 * (wA1 * eA3 + wB1 * eA2) + wB0 * (wA1 * eB3 + wB1 * eB2);               \
    r##K.z = (fminf(r##K.z, 1.f) + g) * vm##K.z;                                     \
    g = wA0 * (wA1 * eA4 + wB1 * eA3) + wB0 * (wA1 * eB4 + wB1 * eB3);               \
    r##K.w = (fminf(r##K.w, 1.f) + g) * vm##K.w; }

#define UNIT_WRITE(K)                                                                \
    if (li##K >= HROW && li##K < HROW + TILE && lj##K >= HCOL && lj##K < HCOL + TILE) { \
        *reinterpret_cast<float4*>(outb + (gi0 + li##K) * NN + (gj0 + lj##K)) = r##K; }

__global__ void __launch_bounds__(TPB, 4) tile_kernel(
        const float* __restrict__ occ,
        const float* __restrict__ ws,
        const float* __restrict__ as_,
        const float* __restrict__ ae_,
        float* __restrict__ out) {
    __shared__ float smem[RROW * LROW];

    const int bid  = blockIdx.x;
    const int b    = bid >> 6;
    const int tile = bid & 63;
    const int ti0  = (tile >> 3) * TILE;
    const int tj0  = (tile & 7)  * TILE;
    const int gi0  = ti0 - HROW;
    const int gj0  = tj0 - HCOL;

    const float p0x = as_[2 * b], p0y = as_[2 * b + 1];
    const float p1x = ae_[2 * b], p1y = ae_[2 * b + 1];
    const float dx = p1x - p0x, dy = p1y - p0y;
    const float L  = sqrtf(dx * dx + dy * dy + 1e-12f);
    const float pu0 = dx / L, pu1 = dy / L;
    const float au0 = fabsf(pu0), au1 = fabsf(pu1);
    const int wx0 = (int)floorf(p1x - 32.f * au1);   // identical expr to splat
    const int wy0 = (int)floorf(p1y - 32.f * au0);
    const bool degen = (dx == 0.f && dy == 0.f);
    const float dn  = sqrtf(dx * dx + dy * dy);
    const bool active = dn > 1e-6f;
    const float rdn = fmaxf(dn, 1e-6f);
    const float ru0 = dx / rdn, ru1 = dy / rdn;
    const float s0f = floorf(ru0), s1f = floorf(ru1);
    const float f0 = ru0 - s0f, f1 = ru1 - s1f;
    const int oi = -(int)s0f;
    const int oj = -(int)s1f;
    const float wA0 = 1.f - f0, wB0 = f0;
    const float wA1 = 1.f - f1, wB1 = f1;

    const float* ob   = occ + ((size_t)b << 18);
    const float* wsb  = ws  + (size_t)b * WWIN;
    float*       outb = out + ((size_t)b << 18);

    // excess can only ever live inside window-box (+1/iter spread)
    const bool ovl = (ti0 <= wx0 + WM - 1 + EXP) && (ti0 + TILE - 1 >= wx0 - EXP) &&
                     (tj0 <= wy0 + WM - 1 + EXP) && (tj0 + TILE - 1 >= wy0 - EXP);
    const bool doiters = active && ovl;

    if (!doiters) {
        // pure streaming: interior only, no halo, no LDS
        #pragma unroll
        for (int k = 0; k < 2; ++k) {
            int u  = threadIdx.x + k * TPB;      // 0..1023
            int li = u >> 4;                      // 0..63
            int lj = (u & 15) << 2;               // 0..60
            int gi = ti0 + li, gj = tj0 + lj;
            float4 o4 = *reinterpret_cast<const float4*>(ob + gi * NN + gj);
            float4 v;
            v.x = r0_elem(o4.x, gi, gj + 0, p0x, p0y, pu0, pu1, L, degen, wx0, wy0, wsb);
            v.y = r0_elem(o4.y, gi, gj + 1, p0x, p0y, pu0, pu1, L, degen, wx0, wy0, wsb);
            v.z = r0_elem(o4.z, gi, gj + 2, p0x, p0y, pu0, pu1, L, degen, wx0, wy0, wsb);
            v.w = r0_elem(o4.w, gi, gj + 3, p0x, p0y, pu0, pu1, L, degen, wx0, wy0, wsb);
            *reinterpret_cast<float4*>(outb + gi * NN + gj) = v;
        }
        return;
    }

    const int tid = threadIdx.x;
    UNIT_INIT(0, tid)
    UNIT_INIT(1, tid + TPB)
    UNIT_INIT(2, tid + 2 * TPB)
    UNIT_INIT(3, min(tid + 3 * TPB, UNITS - 1))

    for (int it = 0; it < ITERS; ++it) {
        UNIT_STORE(0) UNIT_STORE(1) UNIT_STORE(2) UNIT_STORE(3)
        __syncthreads();
        UNIT_GATHER(0) UNIT_GATHER(1) UNIT_GATHER(2) UNIT_GATHER(3)
        __syncthreads();
    }

    UNIT_WRITE(0)
    UNIT_WRITE(1)
    UNIT_WRITE(2)
    UNIT_WRITE(3)
}

extern "C" void kernel_launch(void* const* d_in, const int* in_sizes, int n_in,
                              void* d_out, int out_size, void* d_ws, size_t ws_size,
                              hipStream_t stream) {
    const float* occ = (const float*)d_in[0];
    const float* as_ = (const float*)d_in[1];
    const float* ae_ = (const float*)d_in[2];
    float* out = (float*)d_out;
    float* ws  = (float*)d_ws;

    splat_kernel<<<BB, 1024, 0, stream>>>(occ, as_, ae_, ws);

    const int tile_blocks = BB * (NN / TILE) * (NN / TILE);  // 4096
    tile_kernel<<<tile_blocks, TPB, 0, stream>>>(occ, ws, as_, ae_, out);
}

// Round 5
// 122.668 us; speedup vs baseline: 12.0890x; 1.9477x over previous
//
#include <hip/hip_runtime.h>

#define NN   512
#define NN2  (NN * NN)
#define BB   64
#define TILE 64
#define HROW 10
#define HCOL 12
#define RROW (TILE + 2 * HROW)     // 84 region rows
#define LCOL (TILE + 2 * HCOL)     // 88 logical region cols
#define LROW 89                    // LDS row stride (ODD -> bank spread)
#define UNITS (RROW * (LCOL / 4))  // 1848
#define ITERS 10
#define TPB  512
#define WM   68                    // landing-window dim & stride
#define WWIN (WM * WM)             // 4624 floats
#define EXP  16                    // iteration-skip safety margin
#define SLICES 8                   // splat blocks per batch

__device__ __forceinline__ float sigf(float x) { return 1.0f / (1.0f + __expf(-x)); }

__device__ __forceinline__ float maskf(float s, float t, float L) {
    if (fabsf(t) > 30.f || s < -30.f || s > L + 30.f) return 0.f;
    return sigf(3.f - fabsf(t)) * sigf(s) * sigf(L - s);
}

// r0 = pushed density at (gi,gj): base + landing-window mass. s>=L (or degenerate
// direction) => cell splats exactly onto itself with weight 1 => net rho.
__device__ __forceinline__ float r0_elem(float o, int gi, int gj,
        float p0x, float p0y, float pu0, float pu1, float L,
        bool degen, int wx0, int wy0, const float* __restrict__ wsb) {
    float rx = (float)gi - p0x, ry = (float)gj - p0y;
    float s = rx * pu0 + ry * pu1;
    float t = -rx * pu1 + ry * pu0;
    float m = maskf(s, t, L);
    float v = (degen || s >= L) ? o : o * (1.f - m);
    int cx = gi - wx0, cy = gj - wy0;
    if ((unsigned)cx < (unsigned)WM && (unsigned)cy < (unsigned)WM)
        v += wsb[cx * WM + cy];
    return v;
}

// ---------------- Pass 1: band-enumerating splat, 8 blocks per batch ----------------
// The mask band is |t|<=30, s in [-30, L). For each major-axis line (axis where t
// changes slowly), the minor interval is closed-form (width <= 60/max|u| <= 86).
__global__ void __launch_bounds__(256) splat_kernel(
        const float* __restrict__ occ,
        const float* __restrict__ as_,
        const float* __restrict__ ae_,
        float* __restrict__ ws) {
    __shared__ float win[WWIN];
    const int b   = blockIdx.x >> 3;
    const int sl  = blockIdx.x & (SLICES - 1);
    const int tid = threadIdx.x;

    const float p0x = as_[2 * b], p0y = as_[2 * b + 1];
    const float p1x = ae_[2 * b], p1y = ae_[2 * b + 1];
    const float dx = p1x - p0x, dy = p1y - p0y;
    const float L  = sqrtf(dx * dx + dy * dy + 1e-12f);
    const float u0 = dx / L, u1 = dy / L;
    const float au0 = fabsf(u0), au1 = fabsf(u1);
    const int wx0 = (int)floorf(p1x - 32.f * au1);
    const int wy0 = (int)floorf(p1y - 32.f * au0);
    const bool degen = (dx == 0.f && dy == 0.f);

    for (int k = tid; k < WWIN; k += 256) win[k] = 0.f;
    __syncthreads();

    if (!degen) {
        const float* ob = occ + ((size_t)b << 18);
        const bool mj = (au0 >= au1);   // minor axis = j (t fast along j)
        const int wave = tid >> 6;
        const int lane = tid & 63;

        for (int l = wave; l < 64; l += 4) {
            const int a  = sl * 64 + l;          // major coordinate
            const float fa = (float)a;
            float lo, hi;
            bool skip = false;
            if (mj) {
                // t = -(i-p0x)u1 + (j-p0y)u0 ; i = a
                float jc = p0y + (fa - p0x) * u1 / u0;
                float w  = 30.f / au0;
                lo = jc - w; hi = jc + w;
                if (au1 > 1e-4f) {
                    float j1 = p0y + (-30.f - (fa - p0x) * u0) / u1;
                    float j2 = p0y + (L     - (fa - p0x) * u0) / u1;
                    lo = fmaxf(lo, fminf(j1, j2));
                    hi = fminf(hi, fmaxf(j1, j2));
                } else {
                    float sc = (fa - p0x) * u0;
                    skip = (sc < -31.f) || (sc > L + 1.f);
                }
            } else {
                // minor = i: t = -(i-p0x)u1 + (a-p0y)u0
                float ic = p0x + (fa - p0y) * u0 / u1;
                float w  = 30.f / au1;
                lo = ic - w; hi = ic + w;
                if (au0 > 1e-4f) {
                    float i1 = p0x + (-30.f - (fa - p0y) * u1) / u0;
                    float i2 = p0x + (L     - (fa - p0y) * u1) / u0;
                    lo = fmaxf(lo, fminf(i1, i2));
                    hi = fminf(hi, fmaxf(i1, i2));
                } else {
                    float sc = (fa - p0y) * u1;
                    skip = (sc < -31.f) || (sc > L + 1.f);
                }
            }
            if (skip) continue;
            int clo = max((int)floorf(lo) - 1, 0);
            int chi = min((int)ceilf(hi) + 1, NN - 1);

            for (int c = clo + lane; c <= chi; c += 64) {
                int i = mj ? a : c;
                int j = mj ? c : a;
                float rx = (float)i - p0x, ry = (float)j - p0y;
                float s = rx * u0 + ry * u1;
                float t = -rx * u1 + ry * u0;
                if (fabsf(t) > 30.f || s < -30.f || s >= L) continue;  // s>=L: self-splat
                float rho = ob[i * NN + j];
                float mask  = sigf(3.f - fabsf(t)) * sigf(s) * sigf(L - s);
                float moved = rho * mask;
                if (moved <= 1e-10f) continue;
                // landing depends only on t: p1 + t*n
                float xf = p1x - t * u1;
                float yf = p1y + t * u0;
                float x0 = floorf(xf), y0 = floorf(yf);
                float fx = xf - x0, fy = yf - y0;
                int base = ((int)x0 - wx0) * WM + ((int)y0 - wy0);
                atomicAdd(&win[base],          (1.f - fx) * (1.f - fy) * moved);
                atomicAdd(&win[base + 1],      (1.f - fx) * fy * moved);
                atomicAdd(&win[base + WM],     fx * (1.f - fy) * moved);
                atomicAdd(&win[base + WM + 1], fx * fy * moved);
            }
        }
    }
    __syncthreads();
    float* wsb = ws + (size_t)b * WWIN;
    for (int k = tid; k < WWIN; k += 256) {
        float v = win[k];
        if (v != 0.f) atomicAdd(&wsb[k], v);
    }
}

// ---------------- Pass 2: fused base + window + 10 iterations ----------------
#define UNIT_INIT(K, UEXPR)                                                          \
    const int u##K  = (UEXPR);                                                       \
    const int li##K = u##K / 22;                                                     \
    const int lj##K = (u##K - li##K * 22) * 4;                                       \
    float4 r##K, vm##K;                                                              \
    {                                                                                \
        int gi = gi0 + li##K, gj = gj0 + lj##K;                                      \
        bool rok = (gi >= 0) && (gi < NN);                                           \
        vm##K.x = (rok && (unsigned)(gj + 0) < NN) ? 1.f : 0.f;                      \
        vm##K.y = (rok && (unsigned)(gj + 1) < NN) ? 1.f : 0.f;                      \
        vm##K.z = (rok && (unsigned)(gj + 2) < NN) ? 1.f : 0.f;                      \
        vm##K.w = (rok && (unsigned)(gj + 3) < NN) ? 1.f : 0.f;                      \
        float4 v = make_float4(0.f, 0.f, 0.f, 0.f);                                  \
        if (rok) {                                                                   \
            const float* orow = ob + gi * NN;                                        \
            if (gj >= 0 && gj <= NN - 4) {                                           \
                float4 o4 = *reinterpret_cast<const float4*>(orow + gj);             \
                v.x = r0_elem(o4.x, gi, gj + 0, p0x, p0y, pu0, pu1, L, degen, wx0, wy0, wsb); \
                v.y = r0_elem(o4.y, gi, gj + 1, p0x, p0y, pu0, pu1, L, degen, wx0, wy0, wsb); \
                v.z = r0_elem(o4.z, gi, gj + 2, p0x, p0y, pu0, pu1, L, degen, wx0, wy0, wsb); \
                v.w = r0_elem(o4.w, gi, gj + 3, p0x, p0y, pu0, pu1, L, degen, wx0, wy0, wsb); \
            } else {                                                                 \
                if (vm##K.x > 0.f) v.x = r0_elem(orow[gj + 0], gi, gj + 0, p0x, p0y, pu0, pu1, L, degen, wx0, wy0, wsb); \
                if (vm##K.y > 0.f) v.y = r0_elem(orow[gj + 1], gi, gj + 1, p0x, p0y, pu0, pu1, L, degen, wx0, wy0, wsb); \
                if (vm##K.z > 0.f) v.z = r0_elem(orow[gj + 2], gi, gj + 2, p0x, p0y, pu0, pu1, L, degen, wx0, wy0, wsb); \
                if (vm##K.w > 0.f) v.w = r0_elem(orow[gj + 3], gi, gj + 3, p0x, p0y, pu0, pu1, L, degen, wx0, wy0, wsb); \
            }                                                                        \
        }                                                                            \
        r##K = v;                                                                    \
    }                                                                                \
    const int rA##K = min(max(li##K + oi, 0), RROW - 1);                             \
    const int dB##K = (min(max(li##K + oi - 1, 0), RROW - 1) - rA##K) * LROW;        \
    const int wa##K = li##K * LROW + lj##K;                                          \
    const int aA0##K = rA##K * LROW + max(lj##K + oj - 1, 0);                        \
    const int aA1##K = rA##K * LROW + (lj##K + oj + 0);                              \
    const int aA2##K = rA##K * LROW + (lj##K + oj + 1);                              \
    const int aA3##K = rA##K * LROW + (lj##K + oj + 2);                              \
    const int aA4##K = rA##K * LROW + min(lj##K + oj + 3, LCOL - 1);

#define UNIT_STORE(K)                                                                \
    smem[wa##K + 0] = fmaxf(r##K.x - 1.f, 0.f);                                      \
    smem[wa##K + 1] = fmaxf(r##K.y - 1.f, 0.f);                                      \
    smem[wa##K + 2] = fmaxf(r##K.z - 1.f, 0.f);                                      \
    smem[wa##K + 3] = fmaxf(r##K.w - 1.f, 0.f);

#define UNIT_GATHER(K) {                                                             \
    float eA0 = smem[aA0##K], eA1 = smem[aA1##K], eA2 = smem[aA2##K];                \
    float eA3 = smem[aA3##K], eA4 = smem[aA4##K];                                    \
    float eB0 = smem[aA0##K + dB##K], eB1 = smem[aA1##K + dB##K];                    \
    float eB2 = smem[aA2##K + dB##K], eB3 = smem[aA3##K + dB##K];                    \
    float eB4 = smem[aA4##K + dB##K];                                                \
    float g;                                                                         \
    g = wA0 * (wA1 * eA1 + wB1 * eA0) + wB0 * (wA1 * eB1 + wB1 * eB0);               \
    r##K.x = (fminf(r##K.x, 1.f) + g) * vm##K.x;                                     \
    g = wA0 * (wA1 * eA2 + wB1 * eA1) + wB0 * (wA1 * eB2 + wB1 * eB1);               \
    r##K.y = (fminf(r##K.y, 1.f) + g) * vm##K.y;                                     \
    g = wA0 * (wA1 * eA3 + wB1 * eA2) + wB0 * (wA1 * eB3 + wB1 * eB2);               \
    r##K.z = (fminf(r##K.z, 1.f) + g) * vm##K.z;                                     \
    g = wA0 * (wA1 * eA4 + wB1 * eA3) + wB0 * (wA1 * eB4 + wB1 * eB3);               \
    r##K.w = (fminf(r##K.w, 1.f) + g) * vm##K.w; }

#define UNIT_WRITE(K)                                                                \
    if (li##K >= HROW && li##K < HROW + TILE && lj##K >= HCOL && lj##K < HCOL + TILE) { \
        *reinterpret_cast<float4*>(outb + (gi0 + li##K) * NN + (gj0 + lj##K)) = r##K; }

__global__ void __launch_bounds__(TPB, 4) tile_kernel(
        const float* __restrict__ occ,
        const float* __restrict__ ws,
        const float* __restrict__ as_,
        const float* __restrict__ ae_,
        float* __restrict__ out) {
    __shared__ float smem[RROW * LROW];

    const int bid  = blockIdx.x;
    const int b    = bid >> 6;
    const int tile = bid & 63;
    const int ti0  = (tile >> 3) * TILE;
    const int tj0  = (tile & 7)  * TILE;
    const int gi0  = ti0 - HROW;
    const int gj0  = tj0 - HCOL;

    const float p0x = as_[2 * b], p0y = as_[2 * b + 1];
    const float p1x = ae_[2 * b], p1y = ae_[2 * b + 1];
    const float dx = p1x - p0x, dy = p1y - p0y;
    const float L  = sqrtf(dx * dx + dy * dy + 1e-12f);
    const float pu0 = dx / L, pu1 = dy / L;
    const float au0 = fabsf(pu0), au1 = fabsf(pu1);
    const int wx0 = (int)floorf(p1x - 32.f * au1);   // identical expr to splat
    const int wy0 = (int)floorf(p1y - 32.f * au0);
    const bool degen = (dx == 0.f && dy == 0.f);
    const float dn  = sqrtf(dx * dx + dy * dy);
    const bool active = dn > 1e-6f;
    const float rdn = fmaxf(dn, 1e-6f);
    const float ru0 = dx / rdn, ru1 = dy / rdn;
    const float s0f = floorf(ru0), s1f = floorf(ru1);
    const float f0 = ru0 - s0f, f1 = ru1 - s1f;
    const int oi = -(int)s0f;
    const int oj = -(int)s1f;
    const float wA0 = 1.f - f0, wB0 = f0;
    const float wA1 = 1.f - f1, wB1 = f1;

    const float* ob   = occ + ((size_t)b << 18);
    const float* wsb  = ws  + (size_t)b * WWIN;
    float*       outb = out + ((size_t)b << 18);

    // excess can only ever live inside window-box (+1/iter spread)
    const bool ovl = (ti0 <= wx0 + WM - 1 + EXP) && (ti0 + TILE - 1 >= wx0 - EXP) &&
                     (tj0 <= wy0 + WM - 1 + EXP) && (tj0 + TILE - 1 >= wy0 - EXP);
    const bool doiters = active && ovl;

    if (!doiters) {
        // pure streaming: interior only, no halo, no LDS
        #pragma unroll
        for (int k = 0; k < 2; ++k) {
            int u  = threadIdx.x + k * TPB;      // 0..1023
            int li = u >> 4;                      // 0..63
            int lj = (u & 15) << 2;               // 0..60
            int gi = ti0 + li, gj = tj0 + lj;
            float4 o4 = *reinterpret_cast<const float4*>(ob + gi * NN + gj);
            float4 v;
            v.x = r0_elem(o4.x, gi, gj + 0, p0x, p0y, pu0, pu1, L, degen, wx0, wy0, wsb);
            v.y = r0_elem(o4.y, gi, gj + 1, p0x, p0y, pu0, pu1, L, degen, wx0, wy0, wsb);
            v.z = r0_elem(o4.z, gi, gj + 2, p0x, p0y, pu0, pu1, L, degen, wx0, wy0, wsb);
            v.w = r0_elem(o4.w, gi, gj + 3, p0x, p0y, pu0, pu1, L, degen, wx0, wy0, wsb);
            *reinterpret_cast<float4*>(outb + gi * NN + gj) = v;
        }
        return;
    }

    const int tid = threadIdx.x;
    UNIT_INIT(0, tid)
    UNIT_INIT(1, tid + TPB)
    UNIT_INIT(2, tid + 2 * TPB)
    UNIT_INIT(3, min(tid + 3 * TPB, UNITS - 1))

    for (int it = 0; it < ITERS; ++it) {
        UNIT_STORE(0) UNIT_STORE(1) UNIT_STORE(2) UNIT_STORE(3)
        __syncthreads();
        UNIT_GATHER(0) UNIT_GATHER(1) UNIT_GATHER(2) UNIT_GATHER(3)
        __syncthreads();
    }

    UNIT_WRITE(0)
    UNIT_WRITE(1)
    UNIT_WRITE(2)
    UNIT_WRITE(3)
}

extern "C" void kernel_launch(void* const* d_in, const int* in_sizes, int n_in,
                              void* d_out, int out_size, void* d_ws, size_t ws_size,
                              hipStream_t stream) {
    const float* occ = (const float*)d_in[0];
    const float* as_ = (const float*)d_in[1];
    const float* ae_ = (const float*)d_in[2];
    float* out = (float*)d_out;
    float* ws  = (float*)d_ws;

    hipMemsetAsync(ws, 0, (size_t)BB * WWIN * sizeof(float), stream);

    splat_kernel<<<BB * SLICES, 256, 0, stream>>>(occ, as_, ae_, ws);

    const int tile_blocks = BB * (NN / TILE) * (NN / TILE);  // 4096
    tile_kernel<<<tile_blocks, TPB, 0, stream>>>(occ, ws, as_, ae_, out);
}

// Round 6
// 108.762 us; speedup vs baseline: 13.6346x; 1.1279x over previous
//
#include <hip/hip_runtime.h>

#define NN   512
#define NN2  (NN * NN)
#define BB   64
#define ITERS 10
#define WM   68                    // landing-window dim & stride
#define WWIN (WM * WM)             // 4624 floats
#define SLICES 8                   // splat blocks per batch

// redistribution region: window (68) + 12 halo each side
#define RD   92
#define RDU  23                    // RD/4 float4-units per row
#define RUNITS (RD * RDU)          // 2116
#define RST  97                    // LDS row stride (odd -> bank spread)
#define RTPB 1024

__device__ __forceinline__ float sigf(float x) { return 1.0f / (1.0f + __expf(-x)); }

__device__ __forceinline__ float maskf(float s, float t, float L) {
    if (fabsf(t) > 30.f || s < -30.f || s > L + 30.f) return 0.f;
    return sigf(3.f - fabsf(t)) * sigf(s) * sigf(L - s);
}

// base (pushed density without landing mass). s>=L or degenerate => self-splat => rho.
__device__ __forceinline__ float base_elem(float o, int gi, int gj,
        float p0x, float p0y, float pu0, float pu1, float L, bool degen) {
    float rx = (float)gi - p0x, ry = (float)gj - p0y;
    float s = rx * pu0 + ry * pu1;
    float t = -rx * pu1 + ry * pu0;
    float m = maskf(s, t, L);
    return (degen || s >= L) ? o : o * (1.f - m);
}

// ---------------- Pass 1: band-enumerating splat (unchanged) ----------------
__global__ void __launch_bounds__(256) splat_kernel(
        const float* __restrict__ occ,
        const float* __restrict__ as_,
        const float* __restrict__ ae_,
        float* __restrict__ ws) {
    __shared__ float win[WWIN];
    const int b   = blockIdx.x >> 3;
    const int sl  = blockIdx.x & (SLICES - 1);
    const int tid = threadIdx.x;

    const float p0x = as_[2 * b], p0y = as_[2 * b + 1];
    const float p1x = ae_[2 * b], p1y = ae_[2 * b + 1];
    const float dx = p1x - p0x, dy = p1y - p0y;
    const float L  = sqrtf(dx * dx + dy * dy + 1e-12f);
    const float u0 = dx / L, u1 = dy / L;
    const float au0 = fabsf(u0), au1 = fabsf(u1);
    const int wx0 = (int)floorf(p1x - 32.f * au1);
    const int wy0 = (int)floorf(p1y - 32.f * au0);
    const bool degen = (dx == 0.f && dy == 0.f);

    for (int k = tid; k < WWIN; k += 256) win[k] = 0.f;
    __syncthreads();

    if (!degen) {
        const float* ob = occ + ((size_t)b << 18);
        const bool mj = (au0 >= au1);   // minor axis = j (t fast along j)
        const int wave = tid >> 6;
        const int lane = tid & 63;

        for (int l = wave; l < 64; l += 4) {
            const int a  = sl * 64 + l;          // major coordinate
            const float fa = (float)a;
            float lo, hi;
            bool skip = false;
            if (mj) {
                float jc = p0y + (fa - p0x) * u1 / u0;
                float w  = 30.f / au0;
                lo = jc - w; hi = jc + w;
                if (au1 > 1e-4f) {
                    float j1 = p0y + (-30.f - (fa - p0x) * u0) / u1;
                    float j2 = p0y + (L     - (fa - p0x) * u0) / u1;
                    lo = fmaxf(lo, fminf(j1, j2));
                    hi = fminf(hi, fmaxf(j1, j2));
                } else {
                    float sc = (fa - p0x) * u0;
                    skip = (sc < -31.f) || (sc > L + 1.f);
                }
            } else {
                float ic = p0x + (fa - p0y) * u0 / u1;
                float w  = 30.f / au1;
                lo = ic - w; hi = ic + w;
                if (au0 > 1e-4f) {
                    float i1 = p0x + (-30.f - (fa - p0y) * u1) / u0;
                    float i2 = p0x + (L     - (fa - p0y) * u1) / u0;
                    lo = fmaxf(lo, fminf(i1, i2));
                    hi = fminf(hi, fmaxf(i1, i2));
                } else {
                    float sc = (fa - p0y) * u1;
                    skip = (sc < -31.f) || (sc > L + 1.f);
                }
            }
            if (skip) continue;
            int clo = max((int)floorf(lo) - 1, 0);
            int chi = min((int)ceilf(hi) + 1, NN - 1);

            for (int c = clo + lane; c <= chi; c += 64) {
                int i = mj ? a : c;
                int j = mj ? c : a;
                float rx = (float)i - p0x, ry = (float)j - p0y;
                float s = rx * u0 + ry * u1;
                float t = -rx * u1 + ry * u0;
                if (fabsf(t) > 30.f || s < -30.f || s >= L) continue;  // s>=L: self-splat
                float rho = ob[i * NN + j];
                float mask  = sigf(3.f - fabsf(t)) * sigf(s) * sigf(L - s);
                float moved = rho * mask;
                if (moved <= 1e-10f) continue;
                float xf = p1x - t * u1;    // landing depends only on t
                float yf = p1y + t * u0;
                float x0 = floorf(xf), y0 = floorf(yf);
                float fx = xf - x0, fy = yf - y0;
                int base = ((int)x0 - wx0) * WM + ((int)y0 - wy0);
                atomicAdd(&win[base],          (1.f - fx) * (1.f - fy) * moved);
                atomicAdd(&win[base + 1],      (1.f - fx) * fy * moved);
                atomicAdd(&win[base + WM],     fx * (1.f - fy) * moved);
                atomicAdd(&win[base + WM + 1], fx * fy * moved);
            }
        }
    }
    __syncthreads();
    float* wsb = ws + (size_t)b * WWIN;
    for (int k = tid; k < WWIN; k += 256) {
        float v = win[k];
        if (v != 0.f) atomicAdd(&wsb[k], v);
    }
}

// ---------------- Pass 2: pure streaming base write (whole grid) ----------------
__global__ void __launch_bounds__(256) stream_kernel(
        const float* __restrict__ occ,
        const float* __restrict__ as_,
        const float* __restrict__ ae_,
        float* __restrict__ out) {
    int gid = blockIdx.x * 256 + threadIdx.x;   // float4-group id
    int b   = gid >> 16;
    int rem = gid & 65535;
    int i   = rem >> 7;
    int j0  = (rem & 127) << 2;

    const float p0x = as_[2 * b], p0y = as_[2 * b + 1];
    const float p1x = ae_[2 * b], p1y = ae_[2 * b + 1];
    const float dx = p1x - p0x, dy = p1y - p0y;
    const float L  = sqrtf(dx * dx + dy * dy + 1e-12f);
    const float u0 = dx / L, u1 = dy / L;
    const bool degen = (dx == 0.f && dy == 0.f);

    const float* ob   = occ + ((size_t)b << 18);
    float*       outb = out + ((size_t)b << 18);
    float4 o4 = *reinterpret_cast<const float4*>(ob + i * NN + j0);
    float4 v;
    v.x = base_elem(o4.x, i, j0 + 0, p0x, p0y, u0, u1, L, degen);
    v.y = base_elem(o4.y, i, j0 + 1, p0x, p0y, u0, u1, L, degen);
    v.z = base_elem(o4.z, i, j0 + 2, p0x, p0y, u0, u1, L, degen);
    v.w = base_elem(o4.w, i, j0 + 3, p0x, p0y, u0, u1, L, degen);
    *reinterpret_cast<float4*>(outb + i * NN + j0) = v;
}

// ---------------- Pass 3: per-batch region redistribution ----------------
#define RUNIT_INIT(K, UEXPR)                                                         \
    const int u##K  = (UEXPR);                                                       \
    const int li##K = u##K / RDU;                                                    \
    const int lj##K = (u##K - li##K * RDU) * 4;                                      \
    float4 r##K, vm##K;                                                              \
    {                                                                                \
        int gi = rx0 + li##K;                                                        \
        int gj = ry0 + lj##K;                                                        \
        bool rok = (gi >= 0) && (gi < NN);                                           \
        vm##K.x = (rok && (unsigned)(gj + 0) < NN) ? 1.f : 0.f;                      \
        vm##K.y = (rok && (unsigned)(gj + 1) < NN) ? 1.f : 0.f;                      \
        vm##K.z = (rok && (unsigned)(gj + 2) < NN) ? 1.f : 0.f;                      \
        vm##K.w = (rok && (unsigned)(gj + 3) < NN) ? 1.f : 0.f;                      \
        float4 v = make_float4(0.f, 0.f, 0.f, 0.f);                                  \
        if (rok) {                                                                   \
            const float* orow = outb + gi * NN;                                      \
            int cx = li##K - 12;                                                     \
            bool cxok = (unsigned)cx < (unsigned)WM;                                 \
            float* vp = (float*)&v;                                                  \
            const float* vmp = (const float*)&vm##K;                                 \
            _Pragma("unroll")                                                        \
            for (int e = 0; e < 4; ++e) {                                            \
                if (vmp[e] > 0.f) {                                                  \
                    float t = orow[gj + e];                                          \
                    int cy = lj##K + e - 12;                                         \
                    if (cxok && (unsigned)cy < (unsigned)WM) t += wsb[cx * WM + cy]; \
                    vp[e] = t;                                                       \
                }                                                                    \
            }                                                                        \
        }                                                                            \
        r##K = v;                                                                    \
    }                                                                                \
    const int rA##K = min(max(li##K + oi, 0), RD - 1);                               \
    const int dB##K = (min(max(li##K + oi - 1, 0), RD - 1) - rA##K) * RST;           \
    const int wa##K = li##K * RST + lj##K;                                           \
    const int aA0##K = rA##K * RST + max(lj##K + oj - 1, 0);                         \
    const int aA1##K = rA##K * RST + (lj##K + oj + 0);                               \
    const int aA2##K = rA##K * RST + (lj##K + oj + 1);                               \
    const int aA3##K = rA##K * RST + (lj##K + oj + 2);                               \
    const int aA4##K = rA##K * RST + min(lj##K + oj + 3, RD - 1);

#define RUNIT_STORE(K)                                                               \
    smem[wa##K + 0] = fmaxf(r##K.x - 1.f, 0.f);                                      \
    smem[wa##K + 1] = fmaxf(r##K.y - 1.f, 0.f);                                      \
    smem[wa##K + 2] = fmaxf(r##K.z - 1.f, 0.f);                                      \
    smem[wa##K + 3] = fmaxf(r##K.w - 1.f, 0.f);

#define RUNIT_GATHER(K) {                                                            \
    float eA0 = smem[aA0##K], eA1 = smem[aA1##K], eA2 = smem[aA2##K];                \
    float eA3 = smem[aA3##K], eA4 = smem[aA4##K];                                    \
    float eB0 = smem[aA0##K + dB##K], eB1 = smem[aA1##K + dB##K];                    \
    float eB2 = smem[aA2##K + dB##K], eB3 = smem[aA3##K + dB##K];                    \
    float eB4 = smem[aA4##K + dB##K];                                                \
    float g;                                                                         \
    g = wA0 * (wA1 * eA1 + wB1 * eA0) + wB0 * (wA1 * eB1 + wB1 * eB0);               \
    r##K.x = (fminf(r##K.x, 1.f) + g) * vm##K.x;                                     \
    g = wA0 * (wA1 * eA2 + wB1 * eA1) + wB0 * (wA1 * eB2 + wB1 * eB1);               \
    r##K.y = (fminf(r##K.y, 1.f) + g) * vm##K.y;                                     \
    g = wA0 * (wA1 * eA3 + wB1 * eA2) + wB0 * (wA1 * eB3 + wB1 * eB2);               \
    r##K.z = (fminf(r##K.z, 1.f) + g) * vm##K.z;                                     \
    g = wA0 * (wA1 * eA4 + wB1 * eA3) + wB0 * (wA1 * eB4 + wB1 * eB3);               \
    r##K.w = (fminf(r##K.w, 1.f) + g) * vm##K.w; }

#define RUNIT_WRITE(K) {                                                             \
    int gi = rx0 + li##K;                                                            \
    if (gi >= 0 && gi < NN) {                                                        \
        float* orow = outb + gi * NN;                                                \
        int gj = ry0 + lj##K;                                                        \
        if (vm##K.x > 0.f) orow[gj + 0] = r##K.x;                                    \
        if (vm##K.y > 0.f) orow[gj + 1] = r##K.y;                                    \
        if (vm##K.z > 0.f) orow[gj + 2] = r##K.z;                                    \
        if (vm##K.w > 0.f) orow[gj + 3] = r##K.w;                                    \
    } }

__global__ void __launch_bounds__(RTPB) redist_kernel(
        const float* __restrict__ ws,
        const float* __restrict__ as_,
        const float* __restrict__ ae_,
        float* __restrict__ out) {
    __shared__ float smem[RD * RST];
    const int b   = blockIdx.x;
    const int tid = threadIdx.x;

    const float p0x = as_[2 * b], p0y = as_[2 * b + 1];
    const float p1x = ae_[2 * b], p1y = ae_[2 * b + 1];
    const float dx = p1x - p0x, dy = p1y - p0y;
    const float au0_ = fabsf(dx), au1_ = fabsf(dy);
    const float L  = sqrtf(dx * dx + dy * dy + 1e-12f);
    const float pu0 = dx / L, pu1 = dy / L;
    const int wx0 = (int)floorf(p1x - 32.f * fabsf(pu1));  // identical expr to splat
    const int wy0 = (int)floorf(p1y - 32.f * fabsf(pu0));
    const int rx0 = wx0 - 12;
    const int ry0 = wy0 - 12;
    const float dn  = sqrtf(dx * dx + dy * dy);
    const bool active = dn > 1e-6f;
    const float rdn = fmaxf(dn, 1e-6f);
    const float ru0 = dx / rdn, ru1 = dy / rdn;
    const float s0f = floorf(ru0), s1f = floorf(ru1);
    const float f0 = ru0 - s0f, f1 = ru1 - s1f;
    const int oi = -(int)s0f;
    const int oj = -(int)s1f;
    const float wA0 = 1.f - f0, wB0 = f0;
    const float wA1 = 1.f - f1, wB1 = f1;
    (void)au0_; (void)au1_;

    const float* wsb  = ws  + (size_t)b * WWIN;
    float*       outb = out + ((size_t)b << 18);

    RUNIT_INIT(0, tid)
    RUNIT_INIT(1, tid + RTPB)
    RUNIT_INIT(2, min(tid + 2 * RTPB, RUNITS - 1))

    if (active) {
        for (int it = 0; it < ITERS; ++it) {
            RUNIT_STORE(0) RUNIT_STORE(1) RUNIT_STORE(2)
            __syncthreads();
            RUNIT_GATHER(0) RUNIT_GATHER(1) RUNIT_GATHER(2)
            __syncthreads();
        }
    }

    RUNIT_WRITE(0)
    RUNIT_WRITE(1)
    RUNIT_WRITE(2)
}

extern "C" void kernel_launch(void* const* d_in, const int* in_sizes, int n_in,
                              void* d_out, int out_size, void* d_ws, size_t ws_size,
                              hipStream_t stream) {
    const float* occ = (const float*)d_in[0];
    const float* as_ = (const float*)d_in[1];
    const float* ae_ = (const float*)d_in[2];
    float* out = (float*)d_out;
    float* ws  = (float*)d_ws;

    hipMemsetAsync(ws, 0, (size_t)BB * WWIN * sizeof(float), stream);

    splat_kernel<<<BB * SLICES, 256, 0, stream>>>(occ, as_, ae_, ws);

    const int stream_blocks = (BB * NN2 / 4) / 256;   // 16384
    stream_kernel<<<stream_blocks, 256, 0, stream>>>(occ, as_, ae_, out);

    redist_kernel<<<BB, RTPB, 0, stream>>>(ws, as_, ae_, out);
}

// Round 7
// 99.704 us; speedup vs baseline: 14.8734x; 1.0909x over previous
//
#include <hip/hip_runtime.h>

#define NN   512
#define NN2  (NN * NN)
#define BB   64
#define ITERS 10
#define WM   68                    // landing-window dim & stride
#define WWIN (WM * WM)             // 4624 floats
#define SLICES 16                  // splat blocks per batch
#define STPB 512                   // splat threads per block

// redistribution region: window (68) + 12 halo each side
#define RD   92
#define RDU  23                    // RD/4 float4-units per row
#define RUNITS (RD * RDU)          // 2116
#define RST  97                    // LDS row stride (odd -> bank spread)
#define RTPB 1024

__device__ __forceinline__ float sigf(float x) { return 1.0f / (1.0f + __expf(-x)); }

__device__ __forceinline__ float maskf(float s, float t, float L) {
    if (fabsf(t) > 30.f || s < -30.f || s > L + 30.f) return 0.f;
    return sigf(3.f - fabsf(t)) * sigf(s) * sigf(L - s);
}

// base (pushed density without landing mass). s>=L or degenerate => self-splat => rho.
__device__ __forceinline__ float base_elem(float o, int gi, int gj,
        float p0x, float p0y, float pu0, float pu1, float L, bool degen) {
    float rx = (float)gi - p0x, ry = (float)gj - p0y;
    float s = rx * pu0 + ry * pu1;
    float t = -rx * pu1 + ry * pu0;
    float m = maskf(s, t, L);
    return (degen || s >= L) ? o : o * (1.f - m);
}

// ---------------- Pass 1: band-enumerating splat, 16 blocks/batch, 8 waves/block ----
__global__ void __launch_bounds__(STPB) splat_kernel(
        const float* __restrict__ occ,
        const float* __restrict__ as_,
        const float* __restrict__ ae_,
        float* __restrict__ ws) {
    __shared__ float win[WWIN];
    const int b   = blockIdx.x >> 4;
    const int sl  = blockIdx.x & (SLICES - 1);
    const int tid = threadIdx.x;

    const float p0x = as_[2 * b], p0y = as_[2 * b + 1];
    const float p1x = ae_[2 * b], p1y = ae_[2 * b + 1];
    const float dx = p1x - p0x, dy = p1y - p0y;
    const float L  = sqrtf(dx * dx + dy * dy + 1e-12f);
    const float u0 = dx / L, u1 = dy / L;
    const float au0 = fabsf(u0), au1 = fabsf(u1);
    const int wx0 = (int)floorf(p1x - 32.f * au1);
    const int wy0 = (int)floorf(p1y - 32.f * au0);
    const bool degen = (dx == 0.f && dy == 0.f);

    for (int k = tid; k < WWIN; k += STPB) win[k] = 0.f;
    __syncthreads();

    if (!degen) {
        const float* ob = occ + ((size_t)b << 18);
        const bool mj = (au0 >= au1);   // minor axis = j (t fast along j)
        const int wave = tid >> 6;      // 0..7
        const int lane = tid & 63;

        for (int l = wave; l < 32; l += 8) {
            const int a  = sl * 32 + l;          // major coordinate
            const float fa = (float)a;
            float lo, hi;
            bool skip = false;
            if (mj) {
                float jc = p0y + (fa - p0x) * u1 / u0;
                float w  = 30.f / au0;
                lo = jc - w; hi = jc + w;
                if (au1 > 1e-4f) {
                    float j1 = p0y + (-30.f - (fa - p0x) * u0) / u1;
                    float j2 = p0y + (L     - (fa - p0x) * u0) / u1;
                    lo = fmaxf(lo, fminf(j1, j2));
                    hi = fminf(hi, fmaxf(j1, j2));
                } else {
                    float sc = (fa - p0x) * u0;
                    skip = (sc < -31.f) || (sc > L + 1.f);
                }
            } else {
                float ic = p0x + (fa - p0y) * u0 / u1;
                float w  = 30.f / au1;
                lo = ic - w; hi = ic + w;
                if (au0 > 1e-4f) {
                    float i1 = p0x + (-30.f - (fa - p0y) * u1) / u0;
                    float i2 = p0x + (L     - (fa - p0y) * u1) / u0;
                    lo = fmaxf(lo, fminf(i1, i2));
                    hi = fminf(hi, fmaxf(i1, i2));
                } else {
                    float sc = (fa - p0y) * u1;
                    skip = (sc < -31.f) || (sc > L + 1.f);
                }
            }
            if (skip) continue;
            int clo = max((int)floorf(lo) - 1, 0);
            int chi = min((int)ceilf(hi) + 1, NN - 1);

            for (int c = clo + lane; c <= chi; c += 64) {
                int i = mj ? a : c;
                int j = mj ? c : a;
                float rx = (float)i - p0x, ry = (float)j - p0y;
                float s = rx * u0 + ry * u1;
                float t = -rx * u1 + ry * u0;
                if (fabsf(t) > 30.f || s < -30.f || s >= L) continue;  // s>=L: self-splat
                float rho = ob[i * NN + j];
                float mask  = sigf(3.f - fabsf(t)) * sigf(s) * sigf(L - s);
                float moved = rho * mask;
                if (moved <= 1e-10f) continue;
                float xf = p1x - t * u1;    // landing depends only on t
                float yf = p1y + t * u0;
                float x0 = floorf(xf), y0 = floorf(yf);
                float fx = xf - x0, fy = yf - y0;
                int base = ((int)x0 - wx0) * WM + ((int)y0 - wy0);
                atomicAdd(&win[base],          (1.f - fx) * (1.f - fy) * moved);
                atomicAdd(&win[base + 1],      (1.f - fx) * fy * moved);
                atomicAdd(&win[base + WM],     fx * (1.f - fy) * moved);
                atomicAdd(&win[base + WM + 1], fx * fy * moved);
            }
        }
    }
    __syncthreads();
    float* wsb = ws + (size_t)b * WWIN;
    for (int k = tid; k < WWIN; k += STPB) {
        float v = win[k];
        if (v != 0.f) atomicAdd(&wsb[k], v);
    }
}

// ---------------- Pass 2: pure streaming base write (whole grid) ----------------
__global__ void __launch_bounds__(256) stream_kernel(
        const float* __restrict__ occ,
        const float* __restrict__ as_,
        const float* __restrict__ ae_,
        float* __restrict__ out) {
    int gid = blockIdx.x * 256 + threadIdx.x;   // float4-group id
    int b   = gid >> 16;
    int rem = gid & 65535;
    int i   = rem >> 7;
    int j0  = (rem & 127) << 2;

    const float p0x = as_[2 * b], p0y = as_[2 * b + 1];
    const float p1x = ae_[2 * b], p1y = ae_[2 * b + 1];
    const float dx = p1x - p0x, dy = p1y - p0y;
    const float L  = sqrtf(dx * dx + dy * dy + 1e-12f);
    const float u0 = dx / L, u1 = dy / L;
    const bool degen = (dx == 0.f && dy == 0.f);

    const float* ob   = occ + ((size_t)b << 18);
    float*       outb = out + ((size_t)b << 18);
    float4 o4 = *reinterpret_cast<const float4*>(ob + i * NN + j0);
    float4 v;
    v.x = base_elem(o4.x, i, j0 + 0, p0x, p0y, u0, u1, L, degen);
    v.y = base_elem(o4.y, i, j0 + 1, p0x, p0y, u0, u1, L, degen);
    v.z = base_elem(o4.z, i, j0 + 2, p0x, p0y, u0, u1, L, degen);
    v.w = base_elem(o4.w, i, j0 + 3, p0x, p0y, u0, u1, L, degen);
    *reinterpret_cast<float4*>(outb + i * NN + j0) = v;
}

// ---------------- Pass 3: per-batch region redistribution ----------------
#define RUNIT_INIT(K, UEXPR)                                                         \
    const int u##K  = (UEXPR);                                                       \
    const int li##K = u##K / RDU;                                                    \
    const int lj##K = (u##K - li##K * RDU) * 4;                                      \
    float4 r##K, vm##K;                                                              \
    {                                                                                \
        int gi = rx0 + li##K;                                                        \
        int gj = ry0 + lj##K;                                                        \
        bool rok = (gi >= 0) && (gi < NN);                                           \
        vm##K.x = (rok && (unsigned)(gj + 0) < NN) ? 1.f : 0.f;                      \
        vm##K.y = (rok && (unsigned)(gj + 1) < NN) ? 1.f : 0.f;                      \
        vm##K.z = (rok && (unsigned)(gj + 2) < NN) ? 1.f : 0.f;                      \
        vm##K.w = (rok && (unsigned)(gj + 3) < NN) ? 1.f : 0.f;                      \
        float4 v = make_float4(0.f, 0.f, 0.f, 0.f);                                  \
        if (rok) {                                                                   \
            const float* orow = outb + gi * NN;                                      \
            int cx = li##K - 12;                                                     \
            bool cxok = (unsigned)cx < (unsigned)WM;                                 \
            float* vp = (float*)&v;                                                  \
            const float* vmp = (const float*)&vm##K;                                 \
            _Pragma("unroll")                                                        \
            for (int e = 0; e < 4; ++e) {                                            \
                if (vmp[e] > 0.f) {                                                  \
                    float t = orow[gj + e];                                          \
                    int cy = lj##K + e - 12;                                         \
                    if (cxok && (unsigned)cy < (unsigned)WM) t += wsb[cx * WM + cy]; \
                    vp[e] = t;                                                       \
                }                                                                    \
            }                                                                        \
        }                                                                            \
        r##K = v;                                                                    \
    }                                                                                \
    const int rA##K = min(max(li##K + oi, 0), RD - 1);                               \
    const int dB##K = (min(max(li##K + oi - 1, 0), RD - 1) - rA##K) * RST;           \
    const int wa##K = li##K * RST + lj##K;                                           \
    const int aA0##K = rA##K * RST + max(lj##K + oj - 1, 0);                         \
    const int aA1##K = rA##K * RST + (lj##K + oj + 0);                               \
    const int aA2##K = rA##K * RST + (lj##K + oj + 1);                               \
    const int aA3##K = rA##K * RST + (lj##K + oj + 2);                               \
    const int aA4##K = rA##K * RST + min(lj##K + oj + 3, RD - 1);

#define RUNIT_STORE(K)                                                               \
    smem[wa##K + 0] = fmaxf(r##K.x - 1.f, 0.f);                                      \
    smem[wa##K + 1] = fmaxf(r##K.y - 1.f, 0.f);                                      \
    smem[wa##K + 2] = fmaxf(r##K.z - 1.f, 0.f);                                      \
    smem[wa##K + 3] = fmaxf(r##K.w - 1.f, 0.f);

#define RUNIT_GATHER(K) {                                                            \
    float eA0 = smem[aA0##K], eA1 = smem[aA1##K], eA2 = smem[aA2##K];                \
    float eA3 = smem[aA3##K], eA4 = smem[aA4##K];                                    \
    float eB0 = smem[aA0##K + dB##K], eB1 = smem[aA1##K + dB##K];                    \
    float eB2 = smem[aA2##K + dB##K], eB3 = smem[aA3##K + dB##K];                    \
    float eB4 = smem[aA4##K + dB##K];                                                \
    float g;                                                                         \
    g = wA0 * (wA1 * eA1 + wB1 * eA0) + wB0 * (wA1 * eB1 + wB1 * eB0);               \
    r##K.x = (fminf(r##K.x, 1.f) + g) * vm##K.x;                                     \
    g = wA0 * (wA1 * eA2 + wB1 * eA1) + wB0 * (wA1 * eB2 + wB1 * eB1);               \
    r##K.y = (fminf(r##K.y, 1.f) + g) * vm##K.y;                                     \
    g = wA0 * (wA1 * eA3 + wB1 * eA2) + wB0 * (wA1 * eB3 + wB1 * eB2);               \
    r##K.z = (fminf(r##K.z, 1.f) + g) * vm##K.z;                                     \
    g = wA0 * (wA1 * eA4 + wB1 * eA3) + wB0 * (wA1 * eB4 + wB1 * eB3);               \
    r##K.w = (fminf(r##K.w, 1.f) + g) * vm##K.w; }

#define RUNIT_WRITE(K) {                                                             \
    int gi = rx0 + li##K;                                                            \
    if (gi >= 0 && gi < NN) {                                                        \
        float* orow = outb + gi * NN;                                                \
        int gj = ry0 + lj##K;                                                        \
        if (vm##K.x > 0.f) orow[gj + 0] = r##K.x;                                    \
        if (vm##K.y > 0.f) orow[gj + 1] = r##K.y;                                    \
        if (vm##K.z > 0.f) orow[gj + 2] = r##K.z;                                    \
        if (vm##K.w > 0.f) orow[gj + 3] = r##K.w;                                    \
    } }

__global__ void __launch_bounds__(RTPB) redist_kernel(
        const float* __restrict__ ws,
        const float* __restrict__ as_,
        const float* __restrict__ ae_,
        float* __restrict__ out) {
    __shared__ float smem[RD * RST];
    const int b   = blockIdx.x;
    const int tid = threadIdx.x;

    const float p0x = as_[2 * b], p0y = as_[2 * b + 1];
    const float p1x = ae_[2 * b], p1y = ae_[2 * b + 1];
    const float dx = p1x - p0x, dy = p1y - p0y;
    const float L  = sqrtf(dx * dx + dy * dy + 1e-12f);
    const float pu0 = dx / L, pu1 = dy / L;
    const int wx0 = (int)floorf(p1x - 32.f * fabsf(pu1));  // identical expr to splat
    const int wy0 = (int)floorf(p1y - 32.f * fabsf(pu0));
    const int rx0 = wx0 - 12;
    const int ry0 = wy0 - 12;
    const float dn  = sqrtf(dx * dx + dy * dy);
    const bool active = dn > 1e-6f;
    const float rdn = fmaxf(dn, 1e-6f);
    const float ru0 = dx / rdn, ru1 = dy / rdn;
    const float s0f = floorf(ru0), s1f = floorf(ru1);
    const float f0 = ru0 - s0f, f1 = ru1 - s1f;
    const int oi = -(int)s0f;
    const int oj = -(int)s1f;
    const float wA0 = 1.f - f0, wB0 = f0;
    const float wA1 = 1.f - f1, wB1 = f1;

    const float* wsb  = ws  + (size_t)b * WWIN;
    float*       outb = out + ((size_t)b << 18);

    RUNIT_INIT(0, tid)
    RUNIT_INIT(1, tid + RTPB)
    RUNIT_INIT(2, min(tid + 2 * RTPB, RUNITS - 1))

    if (active) {
        for (int it = 0; it < ITERS; ++it) {
            RUNIT_STORE(0) RUNIT_STORE(1) RUNIT_STORE(2)
            __syncthreads();
            RUNIT_GATHER(0) RUNIT_GATHER(1) RUNIT_GATHER(2)
            __syncthreads();
        }
    }

    RUNIT_WRITE(0)
    RUNIT_WRITE(1)
    RUNIT_WRITE(2)
}

extern "C" void kernel_launch(void* const* d_in, const int* in_sizes, int n_in,
                              void* d_out, int out_size, void* d_ws, size_t ws_size,
                              hipStream_t stream) {
    const float* occ = (const float*)d_in[0];
    const float* as_ = (const float*)d_in[1];
    const float* ae_ = (const float*)d_in[2];
    float* out = (float*)d_out;
    float* ws  = (float*)d_ws;

    hipMemsetAsync(ws, 0, (size_t)BB * WWIN * sizeof(float), stream);

    splat_kernel<<<BB * SLICES, STPB, 0, stream>>>(occ, as_, ae_, ws);

    const int stream_blocks = (BB * NN2 / 4) / 256;   // 16384
    stream_kernel<<<stream_blocks, 256, 0, stream>>>(occ, as_, ae_, out);

    redist_kernel<<<BB, RTPB, 0, stream>>>(ws, as_, ae_, out);
}

// Round 8
// 94.833 us; speedup vs baseline: 15.6373x; 1.0514x over previous
//
#include <hip/hip_runtime.h>

#define NN   512
#define NN2  (NN * NN)
#define BB   64
#define ITERS 10
#define WM   68                    // landing-window dim & stride
#define WWIN (WM * WM)             // 4624 floats
#define SLICES 32                  // splat blocks per batch
#define STPB 512                   // splat threads per block
#define LINESPB 16                 // 512 lines / 32 slices
#define CPL 128                    // cells enumerated per line (width<=86 guaranteed)

// redistribution region: window (68) + 12 halo each side
#define RD   92
#define RDU  23                    // RD/4 float4-units per row
#define RUNITS (RD * RDU)          // 2116
#define RST  97                    // LDS row stride (odd -> bank spread)
#define RTPB 1024

__device__ __forceinline__ float sigf(float x) { return 1.0f / (1.0f + __expf(-x)); }

__device__ __forceinline__ float maskf(float s, float t, float L) {
    if (fabsf(t) > 30.f || s < -30.f || s > L + 30.f) return 0.f;
    return sigf(3.f - fabsf(t)) * sigf(s) * sigf(L - s);
}

// base (pushed density without landing mass). s>=L or degenerate => self-splat => rho.
__device__ __forceinline__ float base_elem(float o, int gi, int gj,
        float p0x, float p0y, float pu0, float pu1, float L, bool degen) {
    float rx = (float)gi - p0x, ry = (float)gj - p0y;
    float s = rx * pu0 + ry * pu1;
    float t = -rx * pu1 + ry * pu0;
    float m = maskf(s, t, L);
    return (degen || s >= L) ? o : o * (1.f - m);
}

// ---------------- Pass 1: flattened band splat — 1 cell per thread-iteration ------
// Band |t|<=30 along each major line has minor-width <= 60/|u_major| <= 85 cells.
// Interval center per line: cen = p0_min + (a - p0_maj) * (u_min/u_maj); the ratio
// and half-width are line-independent (hoisted). 128-cell window is complete; the
// exact band test gates all work, so correctness never depends on the window.
__global__ void __launch_bounds__(STPB) splat_kernel(
        const float* __restrict__ occ,
        const float* __restrict__ as_,
        const float* __restrict__ ae_,
        float* __restrict__ ws) {
    __shared__ float win[WWIN];
    const int b   = blockIdx.x >> 5;
    const int sl  = blockIdx.x & (SLICES - 1);
    const int tid = threadIdx.x;

    const float p0x = as_[2 * b], p0y = as_[2 * b + 1];
    const float p1x = ae_[2 * b], p1y = ae_[2 * b + 1];
    const float dx = p1x - p0x, dy = p1y - p0y;
    const float L  = sqrtf(dx * dx + dy * dy + 1e-12f);
    const float u0 = dx / L, u1 = dy / L;
    const float au0 = fabsf(u0), au1 = fabsf(u1);
    const int wx0 = (int)floorf(p1x - 32.f * au1);
    const int wy0 = (int)floorf(p1y - 32.f * au0);
    const bool degen = (dx == 0.f && dy == 0.f);

    for (int k = tid; k < WWIN; k += STPB) win[k] = 0.f;
    __syncthreads();

    if (!degen) {
        const float* ob = occ + ((size_t)b << 18);
        const bool mj = (au0 >= au1);           // major axis = i when au0>=au1
        const float umaj = mj ? u0 : u1;
        const float rr   = (mj ? u1 : u0) / umaj;   // minor/major slope
        const float ww   = 30.f / fabsf(umaj) + 2.f;
        const float pmaj = mj ? p0x : p0y;
        const float pmin = mj ? p0y : p0x;

        #pragma unroll
        for (int k = 0; k < 4; ++k) {
            int cell = k * STPB + tid;           // 0..2047
            int lidx = cell >> 7;                // 0..15
            int off  = cell & (CPL - 1);         // 0..127
            int a    = sl * LINESPB + lidx;      // major coord 0..511
            float fa = (float)a;
            float cen = pmin + (fa - pmaj) * rr;
            int c = (int)floorf(cen - ww) + off;
            if ((unsigned)c > (unsigned)(NN - 1)) continue;
            int i = mj ? a : c;
            int j = mj ? c : a;
            float rx = (float)i - p0x, ry = (float)j - p0y;
            float s = rx * u0 + ry * u1;
            float t = -rx * u1 + ry * u0;
            if (fabsf(t) > 30.f || s < -30.f || s >= L) continue;  // s>=L: self-splat
            float rho = ob[i * NN + j];
            float mask  = sigf(3.f - fabsf(t)) * sigf(s) * sigf(L - s);
            float moved = rho * mask;
            if (moved <= 1e-10f) continue;
            float xf = p1x - t * u1;    // landing depends only on t
            float yf = p1y + t * u0;
            float x0 = floorf(xf), y0 = floorf(yf);
            float fx = xf - x0, fy = yf - y0;
            int base = ((int)x0 - wx0) * WM + ((int)y0 - wy0);
            atomicAdd(&win[base],          (1.f - fx) * (1.f - fy) * moved);
            atomicAdd(&win[base + 1],      (1.f - fx) * fy * moved);
            atomicAdd(&win[base + WM],     fx * (1.f - fy) * moved);
            atomicAdd(&win[base + WM + 1], fx * fy * moved);
        }
    }
    __syncthreads();
    float* wsb = ws + (size_t)b * WWIN;
    for (int k = tid; k < WWIN; k += STPB) {
        float v = win[k];
        if (v != 0.f) atomicAdd(&wsb[k], v);
    }
}

// ---------------- Pass 2: pure streaming base write (whole grid) ----------------
__global__ void __launch_bounds__(256) stream_kernel(
        const float* __restrict__ occ,
        const float* __restrict__ as_,
        const float* __restrict__ ae_,
        float* __restrict__ out) {
    int gid = blockIdx.x * 256 + threadIdx.x;   // float4-group id
    int b   = gid >> 16;
    int rem = gid & 65535;
    int i   = rem >> 7;
    int j0  = (rem & 127) << 2;

    const float p0x = as_[2 * b], p0y = as_[2 * b + 1];
    const float p1x = ae_[2 * b], p1y = ae_[2 * b + 1];
    const float dx = p1x - p0x, dy = p1y - p0y;
    const float L  = sqrtf(dx * dx + dy * dy + 1e-12f);
    const float u0 = dx / L, u1 = dy / L;
    const bool degen = (dx == 0.f && dy == 0.f);

    const float* ob   = occ + ((size_t)b << 18);
    float*       outb = out + ((size_t)b << 18);
    float4 o4 = *reinterpret_cast<const float4*>(ob + i * NN + j0);
    float4 v;
    v.x = base_elem(o4.x, i, j0 + 0, p0x, p0y, u0, u1, L, degen);
    v.y = base_elem(o4.y, i, j0 + 1, p0x, p0y, u0, u1, L, degen);
    v.z = base_elem(o4.z, i, j0 + 2, p0x, p0y, u0, u1, L, degen);
    v.w = base_elem(o4.w, i, j0 + 3, p0x, p0y, u0, u1, L, degen);
    *reinterpret_cast<float4*>(outb + i * NN + j0) = v;
}

// ---------------- Pass 3: per-batch region redistribution ----------------
#define RUNIT_INIT(K, UEXPR)                                                         \
    const int u##K  = (UEXPR);                                                       \
    const int li##K = u##K / RDU;                                                    \
    const int lj##K = (u##K - li##K * RDU) * 4;                                      \
    float4 r##K, vm##K;                                                              \
    {                                                                                \
        int gi = rx0 + li##K;                                                        \
        int gj = ry0 + lj##K;                                                        \
        bool rok = (gi >= 0) && (gi < NN);                                           \
        vm##K.x = (rok && (unsigned)(gj + 0) < NN) ? 1.f : 0.f;                      \
        vm##K.y = (rok && (unsigned)(gj + 1) < NN) ? 1.f : 0.f;                      \
        vm##K.z = (rok && (unsigned)(gj + 2) < NN) ? 1.f : 0.f;                      \
        vm##K.w = (rok && (unsigned)(gj + 3) < NN) ? 1.f : 0.f;                      \
        float4 v = make_float4(0.f, 0.f, 0.f, 0.f);                                  \
        if (rok) {                                                                   \
            const float* orow = outb + gi * NN;                                      \
            int cx = li##K - 12;                                                     \
            bool cxok = (unsigned)cx < (unsigned)WM;                                 \
            float* vp = (float*)&v;                                                  \
            const float* vmp = (const float*)&vm##K;                                 \
            _Pragma("unroll")                                                        \
            for (int e = 0; e < 4; ++e) {                                            \
                if (vmp[e] > 0.f) {                                                  \
                    float t = orow[gj + e];                                          \
                    int cy = lj##K + e - 12;                                         \
                    if (cxok && (unsigned)cy < (unsigned)WM) t += wsb[cx * WM + cy]; \
                    vp[e] = t;                                                       \
                }                                                                    \
            }                                                                        \
        }                                                                            \
        r##K = v;                                                                    \
    }                                                                                \
    const int rA##K = min(max(li##K + oi, 0), RD - 1);                               \
    const int dB##K = (min(max(li##K + oi - 1, 0), RD - 1) - rA##K) * RST;           \
    const int wa##K = li##K * RST + lj##K;                                           \
    const int aA0##K = rA##K * RST + max(lj##K + oj - 1, 0);                         \
    const int aA1##K = rA##K * RST + (lj##K + oj + 0);                               \
    const int aA2##K = rA##K * RST + (lj##K + oj + 1);                               \
    const int aA3##K = rA##K * RST + (lj##K + oj + 2);                               \
    const int aA4##K = rA##K * RST + min(lj##K + oj + 3, RD - 1);

#define RUNIT_STORE(K)                                                               \
    smem[wa##K + 0] = fmaxf(r##K.x - 1.f, 0.f);                                      \
    smem[wa##K + 1] = fmaxf(r##K.y - 1.f, 0.f);                                      \
    smem[wa##K + 2] = fmaxf(r##K.z - 1.f, 0.f);                                      \
    smem[wa##K + 3] = fmaxf(r##K.w - 1.f, 0.f);

#define RUNIT_GATHER(K) {                                                            \
    float eA0 = smem[aA0##K], eA1 = smem[aA1##K], eA2 = smem[aA2##K];                \
    float eA3 = smem[aA3##K], eA4 = smem[aA4##K];                                    \
    float eB0 = smem[aA0##K + dB##K], eB1 = smem[aA1##K + dB##K];                    \
    float eB2 = smem[aA2##K + dB##K], eB3 = smem[aA3##K + dB##K];                    \
    float eB4 = smem[aA4##K + dB##K];                                                \
    float g;                                                                         \
    g = wA0 * (wA1 * eA1 + wB1 * eA0) + wB0 * (wA1 * eB1 + wB1 * eB0);               \
    r##K.x = (fminf(r##K.x, 1.f) + g) * vm##K.x;                                     \
    g = wA0 * (wA1 * eA2 + wB1 * eA1) + wB0 * (wA1 * eB2 + wB1 * eB1);               \
    r##K.y = (fminf(r##K.y, 1.f) + g) * vm##K.y;                                     \
    g = wA0 * (wA1 * eA3 + wB1 * eA2) + wB0 * (wA1 * eB3 + wB1 * eB2);               \
    r##K.z = (fminf(r##K.z, 1.f) + g) * vm##K.z;                                     \
    g = wA0 * (wA1 * eA4 + wB1 * eA3) + wB0 * (wA1 * eB4 + wB1 * eB3);               \
    r##K.w = (fminf(r##K.w, 1.f) + g) * vm##K.w; }

#define RUNIT_WRITE(K) {                                                             \
    int gi = rx0 + li##K;                                                            \
    if (gi >= 0 && gi < NN) {                                                        \
        float* orow = outb + gi * NN;                                                \
        int gj = ry0 + lj##K;                                                        \
        if (vm##K.x > 0.f) orow[gj + 0] = r##K.x;                                    \
        if (vm##K.y > 0.f) orow[gj + 1] = r##K.y;                                    \
        if (vm##K.z > 0.f) orow[gj + 2] = r##K.z;                                    \
        if (vm##K.w > 0.f) orow[gj + 3] = r##K.w;                                    \
    } }

__global__ void __launch_bounds__(RTPB) redist_kernel(
        const float* __restrict__ ws,
        const float* __restrict__ as_,
        const float* __restrict__ ae_,
        float* __restrict__ out) {
    __shared__ float smem[RD * RST];
    const int b   = blockIdx.x;
    const int tid = threadIdx.x;

    const float p0x = as_[2 * b], p0y = as_[2 * b + 1];
    const float p1x = ae_[2 * b], p1y = ae_[2 * b + 1];
    const float dx = p1x - p0x, dy = p1y - p0y;
    const float L  = sqrtf(dx * dx + dy * dy + 1e-12f);
    const float pu0 = dx / L, pu1 = dy / L;
    const int wx0 = (int)floorf(p1x - 32.f * fabsf(pu1));  // identical expr to splat
    const int wy0 = (int)floorf(p1y - 32.f * fabsf(pu0));
    const int rx0 = wx0 - 12;
    const int ry0 = wy0 - 12;
    const float dn  = sqrtf(dx * dx + dy * dy);
    const bool active = dn > 1e-6f;
    const float rdn = fmaxf(dn, 1e-6f);
    const float ru0 = dx / rdn, ru1 = dy / rdn;
    const float s0f = floorf(ru0), s1f = floorf(ru1);
    const float f0 = ru0 - s0f, f1 = ru1 - s1f;
    const int oi = -(int)s0f;
    const int oj = -(int)s1f;
    const float wA0 = 1.f - f0, wB0 = f0;
    const float wA1 = 1.f - f1, wB1 = f1;

    const float* wsb  = ws  + (size_t)b * WWIN;
    float*       outb = out + ((size_t)b << 18);

    RUNIT_INIT(0, tid)
    RUNIT_INIT(1, tid + RTPB)
    RUNIT_INIT(2, min(tid + 2 * RTPB, RUNITS - 1))

    if (active) {
        for (int it = 0; it < ITERS; ++it) {
            RUNIT_STORE(0) RUNIT_STORE(1) RUNIT_STORE(2)
            __syncthreads();
            RUNIT_GATHER(0) RUNIT_GATHER(1) RUNIT_GATHER(2)
            __syncthreads();
        }
    }

    RUNIT_WRITE(0)
    RUNIT_WRITE(1)
    RUNIT_WRITE(2)
}

extern "C" void kernel_launch(void* const* d_in, const int* in_sizes, int n_in,
                              void* d_out, int out_size, void* d_ws, size_t ws_size,
                              hipStream_t stream) {
    const float* occ = (const float*)d_in[0];
    const float* as_ = (const float*)d_in[1];
    const float* ae_ = (const float*)d_in[2];
    float* out = (float*)d_out;
    float* ws  = (float*)d_ws;

    hipMemsetAsync(ws, 0, (size_t)BB * WWIN * sizeof(float), stream);

    splat_kernel<<<BB * SLICES, STPB, 0, stream>>>(occ, as_, ae_, ws);

    const int stream_blocks = (BB * NN2 / 4) / 256;   // 16384
    stream_kernel<<<stream_blocks, 256, 0, stream>>>(occ, as_, ae_, out);

    redist_kernel<<<BB, RTPB, 0, stream>>>(ws, as_, ae_, out);
}